// Round 9
// baseline (236.049 us; speedup 1.0000x reference)
//
#include <hip/hip_runtime.h>
#include <stdint.h>

typedef unsigned short ushort_t;
typedef __attribute__((ext_vector_type(8))) __bf16 bf16x8;
typedef __attribute__((ext_vector_type(4))) float f32x4;

__device__ __forceinline__ float b2f(ushort_t u) {
    unsigned v = ((unsigned)u) << 16;
    float f;
    __builtin_memcpy(&f, &v, 4);
    return f;
}

// RNE f32->bf16 via compiler cast (v_cvt path on gfx950; identical RNE
// rounding to the old integer sequence, ~4 ops cheaper).
__device__ __forceinline__ ushort_t f2b(float f) {
    __bf16 h = (__bf16)f;
    return __builtin_bit_cast(ushort_t, h);
}

__device__ __forceinline__ void gl_lds16(const void* g, void* l) {
    __builtin_amdgcn_global_load_lds((const __attribute__((address_space(1))) void*)g,
                                     (__attribute__((address_space(3))) void*)l, 16, 0, 0);
}

// ---------------------------------------------------------------------------
// Fused preprocessing: w0/w1 bf16-cvt, sdat build, points2 transpose, and
// zeroing of the global BN-stat accumulators (re-zeroed every graph replay).
__global__ __launch_bounds__(256) void k_pre(const float* __restrict__ w0, ushort_t* __restrict__ w0b,
                                             const float* __restrict__ w1, ushort_t* __restrict__ w1b,
                                             const float* __restrict__ xyz2, float4* __restrict__ sdat,
                                             const float* __restrict__ points2, ushort_t* __restrict__ p2t,
                                             float* __restrict__ zb) {
    int bid = blockIdx.x;
    int t = threadIdx.x;
    if (bid < 512) {
        int i = bid * 256 + t;
        w0b[i] = f2b(w0[i]);
    } else if (bid < 640) {
        int i = (bid - 512) * 256 + t;
        w1b[i] = f2b(w1[i]);
    } else if (bid < 704) {
        int bb = bid - 640;
        int b = bb & 15, by = bb >> 4;
        int s = by * 256 + t;
        const float* x2 = xyz2 + (size_t)b * 3 * 1024;
        float x = x2[s], y = x2[1024 + s], z = x2[2048 + s];
        float4 v;
        v.x = x; v.y = y; v.z = z;
        v.w = __fadd_rn(__fadd_rn(__fmul_rn(x, x), __fmul_rn(y, y)), __fmul_rn(z, z));
        sdat[(size_t)b * 1024 + s] = v;
    } else if (bid < 960) {
        int bb = bid - 704;
        int b = bb & 15, sy = bb >> 4;
        int s = sy * 64 + (t & 63);
        int g = t >> 6;
        const float* src = points2 + (size_t)b * 128 * 1024 + s;
        ushort_t* dst = p2t + ((size_t)b * 1024 + s) * 128;
#pragma unroll
        for (int i = 0; i < 4; ++i) {
            int cp = i * 4 + g;
            ushort_t tmp[8];
#pragma unroll
            for (int k = 0; k < 8; ++k) tmp[k] = f2b(src[(size_t)(cp * 8 + k) * 1024]);
            *(uint4*)(dst + cp * 8) = *(const uint4*)tmp;
        }
    } else {
        // zero gs0[256] gq0[256] gs1[128] gq1[128]
        zb[t] = 0.f; zb[256 + t] = 0.f;
        if (t < 128) { zb[512 + t] = 0.f; zb[640 + t] = 0.f; }
    }
}

// ---------------------------------------------------------------------------
// 3-NN: 32 queries/block, 8 slices x 128 points. Outputs sidx/sw + Xp1.
// Scan/merge math bit-identical to the verified version.
__global__ __launch_bounds__(256) void k_interp(const float* __restrict__ xyz1,
                                                const float4* __restrict__ sdat,
                                                const float* __restrict__ points1,
                                                ushort_t* __restrict__ Xp1,
                                                int* __restrict__ sidxg,
                                                float* __restrict__ swg) {
    int b = blockIdx.x;
    int n0 = blockIdx.y * 32;
    int t = threadIdx.x;
    int tq = t & 31;        // query within block
    int slice = t >> 5;     // 0..7
    int wave = t >> 6, lane = t & 63;

    __shared__ __align__(16) char sbuf[16384];  // sP: staged sdat[b]
    float4* sP = (float4*)sbuf;
    __shared__ float sD[768];
    __shared__ int   sI[768];

    // stage sdat[b] -> LDS (wave w loads points [w*256, w*256+256))
    {
        const float4* src = sdat + (size_t)b * 1024;
#pragma unroll
        for (int c = 0; c < 4; ++c) {
            int p = wave * 256 + c * 64 + lane;
            gl_lds16(src + p, sbuf + p * 16);
        }
    }

    int n = n0 + tq;
    float x = xyz1[((size_t)b * 3 + 0) * 4096 + n];
    float y = xyz1[((size_t)b * 3 + 1) * 4096 + n];
    float z = xyz1[((size_t)b * 3 + 2) * 4096 + n];
    float s1 = __fadd_rn(__fadd_rn(__fmul_rn(x, x), __fmul_rn(y, y)), __fmul_rn(z, z));

    __syncthreads();   // staging complete (drains all vmcnt incl. gl_lds)

    // Issue points1 loads now: they ride out the scan in the vmem queue.
    const float* p1base = points1 + (size_t)b * 128 * 4096 + n0 + tq;
    float p1v[16];
#pragma unroll
    for (int i = 0; i < 2; ++i)
#pragma unroll
        for (int k = 0; k < 8; ++k)
            p1v[i * 8 + k] = p1base[(size_t)(((i * 8 + slice) * 8) + k) * 4096];

    float d0 = 1e30f, d1 = 1e30f, d2 = 1e30f;
    int i0 = 0, i1 = 0, i2 = 0;
    int sbeg = slice * 128;
    const float4* sdL = sP + sbeg;
#pragma unroll 8
    for (int s = 0; s < 128; ++s) {
        float4 v = sdL[s];
        float dot = fmaf(z, v.z, fmaf(y, v.y, __fmul_rn(x, v.x)));
        // fmaf(-2,dot,s1) == add(mul(-2,dot),s1) bit-exactly: *2 is exact.
        float d = __fadd_rn(fmaf(-2.0f, dot, s1), v.w);
        int si = sbeg + s;
        bool c0 = d < d0, c1 = d < d1, c2 = d < d2;
        // indices: identical logic to the verified version
        i2 = c1 ? i1 : (c2 ? si : i2);
        i1 = c0 ? i0 : (c1 ? si : i1);
        i0 = c0 ? si : i0;
        // distances: min/max forms select bit-identical values
        d2 = fminf(fmaxf(d, d1), d2);
        d1 = fminf(fmaxf(d, d0), d1);
        d0 = fminf(d, d0);
    }
    sD[t * 3 + 0] = d0; sD[t * 3 + 1] = d1; sD[t * 3 + 2] = d2;
    sI[t * 3 + 0] = i0; sI[t * 3 + 1] = i1; sI[t * 3 + 2] = i2;

    // points1 part: Xp1[j][0:128] = bf16(points1[b][:, n]) (loads done above)
    {
        ushort_t* dstbase = Xp1 + (size_t)(b * 4096 + n0 + tq) * 128;
#pragma unroll
        for (int i = 0; i < 2; ++i) {
            int piece = i * 8 + slice;
            ushort_t tmp[8];
#pragma unroll
            for (int k = 0; k < 8; ++k) tmp[k] = f2b(p1v[i * 8 + k]);
            *(uint4*)(dstbase + piece * 8) = *(const uint4*)tmp;
        }
    }
    __syncthreads();   // scan + sD/sI complete

    // merge: threads t<32 pick global top-3 of 24 candidates by lex (d, idx),
    // then write (sidx, sw) straight to global.
    if (t < 32) {
        int sel0 = -1, sel1 = -1;
        float seld[3]; int seli[3];
#pragma unroll
        for (int r = 0; r < 3; ++r) {
            float bd = 1e38f; int bi = 1 << 30;
            for (int k = 0; k < 24; ++k) {
                int s3 = (k * 0xAAAB) >> 17;    // k/3 for k<=23
                int rank = k - s3 * 3;
                int base = (s3 * 32 + t) * 3 + rank;
                float cd = sD[base];
                int ci = sI[base];
                bool excl = (ci == sel0) | (ci == sel1);
                bool better = (!excl) & ((cd < bd) | ((cd == bd) & (ci < bi)));
                if (better) { bd = cd; bi = ci; }
            }
            seld[r] = bd; seli[r] = bi;
            if (r == 0) sel0 = bi; else if (r == 1) sel1 = bi;
        }
        float r0 = 1.0f / (seld[0] + 1e-8f);
        float r1 = 1.0f / (seld[1] + 1e-8f);
        float r2 = 1.0f / (seld[2] + 1e-8f);
        float rs = r0 + r1 + r2;
        size_t base = (size_t)(b * 4096 + n0 + t) * 3;
        sidxg[base + 0] = seli[0]; sidxg[base + 1] = seli[1]; sidxg[base + 2] = seli[2];
        swg[base + 0] = r0 / rs; swg[base + 1] = r1 / rs; swg[base + 2] = r2 / rs;
    }
}

// ---------------------------------------------------------------------------
// GEMM0 with fused interp-gather B-staging (round-7 design; round-8 init fix;
// this round adds a defensive si&1023 clamp — bit-identical for valid data,
// prevents wild reads from ever poisoning the container again):
//  * T2 XOR swizzle (both-sides, rule 21): chunk kc of row r sits at LDS
//    position kc^(r&7). gl_lds16 tiles pre-swizzle the GLOBAL source; the
//    reg-staged gather swizzles the LDS write; MFMA reads XOR with l16&7.
//  * T14 async-stage: gather loads for kt+1 issued to REGISTERS before kt's
//    barrier; scaled+written at kt+1. kt loop fully unrolled (rule 20).
//  * BM=128, 256-thread blocks, LDS 36 KB -> 4 blocks/CU.
// Gather expression f2b(w*b2f(p2t)) unchanged -> GEMM inputs bit-identical.
__global__ __launch_bounds__(256, 4) void k_gemm(const ushort_t* __restrict__ A,
                                                 const ushort_t* __restrict__ Xp1,
                                                 const ushort_t* __restrict__ p2t,
                                                 const int* __restrict__ sidxg,
                                                 const float* __restrict__ swg,
                                                 const float* __restrict__ bias,
                                                 ushort_t* __restrict__ Y,
                                                 float* __restrict__ gs,
                                                 float* __restrict__ gq,
                                                 int Mtot, int K) {
    __shared__ __align__(16) char smem[36864];
    ushort_t* As = (ushort_t*)smem;               // 128 x 64 bf16, swizzled
    ushort_t* Bs = (ushort_t*)(smem + 16384);     // 128 x 64 bf16, swizzled
    int*   lsi   = (int*)(smem + 32768);          // 384 ints
    float* lsw   = (float*)(smem + 34304);        // 384 floats
    ushort_t* sY = (ushort_t*)smem;               // epilogue reuse (34816 B)
    float* red_s = (float*)(smem + 35840);        // 128
    float* red_q = red_s + 128;                   // 128

    int t = threadIdx.x;
    int m0 = blockIdx.x * 128;
    int j0 = blockIdx.y * 128;
    int b = (j0 >> 12) & 15;                      // batch (4096 rows/batch)
    int wave = t >> 6, lane = t & 63;
    int wm = wave >> 1, wn = wave & 1;
    int l16 = lane & 15, quad = lane >> 4;
    int sw7 = l16 & 7;

    if (t < 128) { red_s[t] = 0.f; red_q[t] = 0.f; }
    // strided init: 256 threads cover 384 entries (round-7 crash fix)
    for (int i = t; i < 384; i += 256) {
        lsi[i] = sidxg[(size_t)j0 * 3 + i] & 1023;   // clamp: defensive, free
        lsw[i] = swg[(size_t)j0 * 3 + i];
    }

    f32x4 acc[4][4] = {};
    uint4 bpreA[4], bpreB[4];                      // gather prefetch dbuf
    (void)K;

#pragma unroll
    for (int kt = 0; kt < 8; ++kt) {
        // ---- A stage (gl_lds16, source pre-swizzled) ----
#pragma unroll
        for (int c = 0; c < 4; ++c) {
            int idx = c * 256 + t;
            int row = idx >> 3, kc = idx & 7;
            gl_lds16(A + (size_t)(m0 + row) * 512 + kt * 64 + ((kc ^ (row & 7)) * 8),
                     As + idx * 8);
        }
        // ---- B provide for this kt ----
        if (kt < 2) {
            // points1 block via gl_lds16, source pre-swizzled
#pragma unroll
            for (int c = 0; c < 4; ++c) {
                int idx = c * 256 + t;
                int row = idx >> 3, kc = idx & 7;
                gl_lds16(Xp1 + (size_t)(j0 + row) * 128 + kt * 64 + ((kc ^ (row & 7)) * 8),
                         Bs + idx * 8);
            }
        } else {
            // write prefetched gather regs (scaled), swizzled LDS address
            int r = (kt - 2) >> 1;
#pragma unroll
            for (int c = 0; c < 4; ++c) {
                int idx = c * 256 + t;
                int row = idx >> 3, kc = idx & 7;
                float w = lsw[row * 3 + r];
                uint4 raw = (kt & 1) ? bpreB[c] : bpreA[c];
                ushort_t* e = (ushort_t*)&raw;
                ushort_t outv[8];
#pragma unroll
                for (int k = 0; k < 8; ++k) outv[k] = f2b(w * b2f(e[k]));
                *(uint4*)(Bs + row * 64 + ((kc ^ (row & 7)) * 8)) = *(const uint4*)outv;
            }
        }
        // ---- issue next-kt gather loads (fly across barrier + MFMA) ----
        if (kt + 1 >= 2 && kt + 1 < 8) {
            int rn = (kt - 1) >> 1, hn = (kt - 1) & 1;
#pragma unroll
            for (int c = 0; c < 4; ++c) {
                int idx = c * 256 + t;
                int row = idx >> 3, kc = idx & 7;
                int si = lsi[row * 3 + rn] & 1023;
                uint4 v = *(const uint4*)(p2t + (((size_t)b * 1024 + si) * 128) + hn * 64 + kc * 8);
                if ((kt + 1) & 1) bpreB[c] = v; else bpreA[c] = v;
            }
        }
        __syncthreads();

#pragma unroll
        for (int kk = 0; kk < 2; ++kk) {
            bf16x8 af[4], bfr[4];
#pragma unroll
            for (int mi = 0; mi < 4; ++mi)
                af[mi] = *(const bf16x8*)(As + (wm * 64 + mi * 16 + l16) * 64 + (((kk * 4 + quad) ^ sw7) * 8));
#pragma unroll
            for (int ni = 0; ni < 4; ++ni)
                bfr[ni] = *(const bf16x8*)(Bs + (wn * 64 + ni * 16 + l16) * 64 + (((kk * 4 + quad) ^ sw7) * 8));
#pragma unroll
            for (int mi = 0; mi < 4; ++mi)
#pragma unroll
                for (int ni = 0; ni < 4; ++ni)
                    acc[mi][ni] = __builtin_amdgcn_mfma_f32_16x16x32_bf16(af[mi], bfr[ni], acc[mi][ni], 0, 0, 0);
        }
        __syncthreads();
    }

#pragma unroll
    for (int mi = 0; mi < 4; ++mi) {
        int obase = wm * 64 + mi * 16 + quad * 4;
        float bv[4];
#pragma unroll
        for (int r = 0; r < 4; ++r) bv[r] = bias[m0 + obase + r];
        float sr[4] = {0.f, 0.f, 0.f, 0.f}, qr[4] = {0.f, 0.f, 0.f, 0.f};
#pragma unroll
        for (int ni = 0; ni < 4; ++ni) {
            int j_local = wn * 64 + ni * 16 + l16;
            ushort4 pk;
            float v0 = acc[mi][ni][0] + bv[0];
            float v1 = acc[mi][ni][1] + bv[1];
            float v2 = acc[mi][ni][2] + bv[2];
            float v3 = acc[mi][ni][3] + bv[3];
            pk.x = f2b(v0); pk.y = f2b(v1); pk.z = f2b(v2); pk.w = f2b(v3);
            sr[0] += v0; qr[0] += v0 * v0;
            sr[1] += v1; qr[1] += v1 * v1;
            sr[2] += v2; qr[2] += v2 * v2;
            sr[3] += v3; qr[3] += v3 * v3;
            *(ushort4*)(sY + j_local * 136 + obase) = pk;
        }
#pragma unroll
        for (int r = 0; r < 4; ++r) {
            float s = sr[r], q = qr[r];
            s += __shfl_xor(s, 1); s += __shfl_xor(s, 2);
            s += __shfl_xor(s, 4); s += __shfl_xor(s, 8);
            q += __shfl_xor(q, 1); q += __shfl_xor(q, 2);
            q += __shfl_xor(q, 4); q += __shfl_xor(q, 8);
            if (l16 == 0) {
                atomicAdd(&red_s[obase + r], s);
                atomicAdd(&red_q[obase + r], q);
            }
        }
    }
    __syncthreads();

#pragma unroll
    for (int rep = 0; rep < 8; ++rep) {
        int idx = rep * 256 + t;
        int jl = idx >> 4;
        int o8 = idx & 15;
        uint4 vv = *(const uint4*)(sY + jl * 136 + o8 * 8);
        *(uint4*)(Y + (size_t)(j0 + jl) * Mtot + m0 + o8 * 8) = vv;
    }
    if (t < 128) {
        atomicAdd(&gs[m0 + t], red_s[t]);
        atomicAdd(&gq[m0 + t], red_q[t]);
    }
}

// ---------------------------------------------------------------------------
// GEMM1: fused BN0 finalize in prologue + BN0+ReLU at B staging. Same T2
// XOR swizzle as k_gemm (A source pre-swizzled; B write + reads swizzled).
__global__ __launch_bounds__(256) void k_gemmf(const ushort_t* __restrict__ A,
                                               const ushort_t* __restrict__ Y0,
                                               const float* __restrict__ bias,
                                               const float* __restrict__ gamma0,
                                               const float* __restrict__ beta0,
                                               const float* __restrict__ gs0,
                                               const float* __restrict__ gq0,
                                               ushort_t* __restrict__ Y,
                                               float* __restrict__ gs1,
                                               float* __restrict__ gq1,
                                               int Mtot, int K) {
    __shared__ __align__(16) char smem[35840];
    ushort_t* As = (ushort_t*)smem;               // 128 x 64, swizzled
    ushort_t* Bs = (ushort_t*)(smem + 16384);     // 128 x 64, swizzled
    float* sa = (float*)(smem + 32768);           // 256 floats
    float* sb = (float*)(smem + 33792);           // 256 floats
    ushort_t* sY = (ushort_t*)smem;               // epilogue reuse
    float* red_s = (float*)(smem + 34816);
    float* red_q = red_s + 128;

    int t = threadIdx.x;
    int m0 = blockIdx.x * 128;
    int j0 = blockIdx.y * 128;
    int wave = t >> 6, lane = t & 63;
    int wm = wave >> 1, wn = wave & 1;
    int l16 = lane & 15, quad = lane >> 4;
    int sw7 = l16 & 7;

    // BN0 finalize (identical math to the former k_bnfin)
    {
        float s = gs0[t], q = gq0[t];
        float mean = s * (1.0f / 65536.0f);
        float var = q * (1.0f / 65536.0f) - mean * mean;
        float sc = gamma0[t] / sqrtf(var + 1e-5f);
        sa[t] = sc;
        sb[t] = beta0[t] - mean * sc;
    }
    if (t < 128) { red_s[t] = 0.f; red_q[t] = 0.f; }
    __syncthreads();

    f32x4 acc[4][4] = {};

    int nk = K >> 6;
    for (int kt = 0; kt < nk; ++kt) {
#pragma unroll
        for (int c = 0; c < 4; ++c) {
            int idx = c * 256 + t;
            int row = idx >> 3, kc = idx & 7;
            gl_lds16(A + (size_t)(m0 + row) * K + kt * 64 + ((kc ^ (row & 7)) * 8), As + idx * 8);
        }
#pragma unroll
        for (int c = 0; c < 4; ++c) {
            int idx = c * 256 + t;
            int row = idx >> 3, kc = idx & 7;
            int cbase = kt * 64 + kc * 8;
            uint4 raw = *(const uint4*)(Y0 + (size_t)(j0 + row) * K + cbase);
            ushort_t* e = (ushort_t*)&raw;
            ushort_t outv[8];
#pragma unroll
            for (int k = 0; k < 8; ++k) {
                float v = fmaxf(sa[cbase + k] * b2f(e[k]) + sb[cbase + k], 0.f);
                outv[k] = f2b(v);
            }
            *(uint4*)(Bs + row * 64 + ((kc ^ (row & 7)) * 8)) = *(const uint4*)outv;
        }
        __syncthreads();

#pragma unroll
        for (int kk = 0; kk < 2; ++kk) {
            bf16x8 af[4], bfr[4];
#pragma unroll
            for (int mi = 0; mi < 4; ++mi)
                af[mi] = *(const bf16x8*)(As + (wm * 64 + mi * 16 + l16) * 64 + (((kk * 4 + quad) ^ sw7) * 8));
#pragma unroll
            for (int ni = 0; ni < 4; ++ni)
                bfr[ni] = *(const bf16x8*)(Bs + (wn * 64 + ni * 16 + l16) * 64 + (((kk * 4 + quad) ^ sw7) * 8));
#pragma unroll
            for (int mi = 0; mi < 4; ++mi)
#pragma unroll
                for (int ni = 0; ni < 4; ++ni)
                    acc[mi][ni] = __builtin_amdgcn_mfma_f32_16x16x32_bf16(af[mi], bfr[ni], acc[mi][ni], 0, 0, 0);
        }
        __syncthreads();
    }

#pragma unroll
    for (int mi = 0; mi < 4; ++mi) {
        int obase = wm * 64 + mi * 16 + quad * 4;
        float bv[4];
#pragma unroll
        for (int r = 0; r < 4; ++r) bv[r] = bias[m0 + obase + r];
        float sr[4] = {0.f, 0.f, 0.f, 0.f}, qr[4] = {0.f, 0.f, 0.f, 0.f};
#pragma unroll
        for (int ni = 0; ni < 4; ++ni) {
            int j_local = wn * 64 + ni * 16 + l16;
            ushort4 pk;
            float v0 = acc[mi][ni][0] + bv[0];
            float v1 = acc[mi][ni][1] + bv[1];
            float v2 = acc[mi][ni][2] + bv[2];
            float v3 = acc[mi][ni][3] + bv[3];
            pk.x = f2b(v0); pk.y = f2b(v1); pk.z = f2b(v2); pk.w = f2b(v3);
            sr[0] += v0; qr[0] += v0 * v0;
            sr[1] += v1; qr[1] += v1 * v1;
            sr[2] += v2; qr[2] += v2 * v2;
            sr[3] += v3; qr[3] += v3 * v3;
            *(ushort4*)(sY + j_local * 136 + obase) = pk;
        }
#pragma unroll
        for (int r = 0; r < 4; ++r) {
            float s = sr[r], q = qr[r];
            s += __shfl_xor(s, 1); s += __shfl_xor(s, 2);
            s += __shfl_xor(s, 4); s += __shfl_xor(s, 8);
            q += __shfl_xor(q, 1); q += __shfl_xor(q, 2);
            q += __shfl_xor(q, 4); q += __shfl_xor(q, 8);
            if (l16 == 0) {
                atomicAdd(&red_s[obase + r], s);
                atomicAdd(&red_q[obase + r], q);
            }
        }
    }
    __syncthreads();

#pragma unroll
    for (int rep = 0; rep < 8; ++rep) {
        int idx = rep * 256 + t;
        int jl = idx >> 4;
        int o8 = idx & 15;
        uint4 vv = *(const uint4*)(sY + jl * 136 + o8 * 8);
        *(uint4*)(Y + (size_t)(j0 + jl) * Mtot + m0 + o8 * 8) = vv;
    }
    if (t < 128) {
        atomicAdd(&gs1[m0 + t], red_s[t]);
        atomicAdd(&gq1[m0 + t], red_q[t]);
    }
}

// ---------------------------------------------------------------------------
// Output: fused BN1 finalize in prologue + BN1+ReLU + fp32 transpose-store.
__global__ __launch_bounds__(256) void k_out(const ushort_t* __restrict__ Y1,
                                             const float* __restrict__ gs1,
                                             const float* __restrict__ gq1,
                                             const float* __restrict__ gamma1,
                                             const float* __restrict__ beta1,
                                             float* __restrict__ out) {
    __shared__ float sa[128], sb[128];
    int t = threadIdx.x;
    if (t < 128) {
        float s = gs1[t], q = gq1[t];
        float mean = s * (1.0f / 65536.0f);
        float var = q * (1.0f / 65536.0f) - mean * mean;
        float sc = gamma1[t] / sqrtf(var + 1e-5f);
        sa[t] = sc;
        sb[t] = beta1[t] - mean * sc;
    }
    __syncthreads();
    int b = blockIdx.x;
    int nl = t & 127;
    int half = t >> 7;
    int n = blockIdx.y * 128 + nl;
    const uint4* src = (const uint4*)(Y1 + (size_t)(b * 4096 + n) * 128);
    float* dst = out + (size_t)b * 128 * 4096 + n;
    uint4 raw[8];
#pragma unroll
    for (int p = 0; p < 8; ++p) raw[p] = src[half * 8 + p];
    const ushort_t* e = (const ushort_t*)raw;
#pragma unroll
    for (int c = 0; c < 64; ++c) {
        int ch = half * 64 + c;
        float v = b2f(e[c]);
        v = fmaxf(sa[ch] * v + sb[ch], 0.f);
        dst[(size_t)ch * 4096] = v;
    }
}

// ---------------------------------------------------------------------------
extern "C" void kernel_launch(void* const* d_in, const int* in_sizes, int n_in,
                              void* d_out, int out_size, void* d_ws, size_t ws_size,
                              hipStream_t stream) {
    const float* xyz1    = (const float*)d_in[0];
    const float* xyz2    = (const float*)d_in[1];
    const float* points1 = (const float*)d_in[2];
    const float* points2 = (const float*)d_in[3];
    const float* w0      = (const float*)d_in[4];
    const float* b0      = (const float*)d_in[5];
    const float* gamma0  = (const float*)d_in[6];
    const float* beta0   = (const float*)d_in[7];
    const float* w1      = (const float*)d_in[8];
    const float* b1      = (const float*)d_in[9];
    const float* gamma1  = (const float*)d_in[10];
    const float* beta1   = (const float*)d_in[11];
    float* out = (float*)d_out;

    char* ws = (char*)d_ws;
    const size_t OFF_XP1  = 0;                       // 16777216
    const size_t OFF_SIDX = 16777216;                // 786432
    const size_t OFF_SW   = 17563648;                // 786432
    const size_t OFF_Y0   = 67108864;                // 33554432
    const size_t OFF_Y1   = 100663296;               // 16777216
    const size_t OFF_P2T  = 117440512;               // 4194304
    const size_t OFF_W0B  = 121634816;               // 262144
    const size_t OFF_W1B  = 121896960;               // 65536
    const size_t OFF_AB   = 121962496;               // 3072 (global stat accum)
    const size_t OFF_SDAT = 121965568;               // 262144

    ushort_t* Xp1  = (ushort_t*)(ws + OFF_XP1);
    int*   sidxg   = (int*)(ws + OFF_SIDX);
    float* swg     = (float*)(ws + OFF_SW);
    ushort_t* Y0   = (ushort_t*)(ws + OFF_Y0);
    ushort_t* Y1   = (ushort_t*)(ws + OFF_Y1);
    ushort_t* p2t  = (ushort_t*)(ws + OFF_P2T);
    ushort_t* w0b  = (ushort_t*)(ws + OFF_W0B);
    ushort_t* w1b  = (ushort_t*)(ws + OFF_W1B);
    float* ab      = (float*)(ws + OFF_AB);
    float4* sdat   = (float4*)(ws + OFF_SDAT);
    float* gs0 = ab;        float* gq0 = ab + 256;
    float* gs1 = ab + 512;  float* gq1 = ab + 640;

    k_pre<<<961, 256, 0, stream>>>(w0, w0b, w1, w1b, xyz2, sdat, points2, p2t, ab);
    k_interp<<<dim3(16, 128), 256, 0, stream>>>(xyz1, sdat, points1, Xp1, sidxg, swg);
    k_gemm<<<dim3(2, 512), 256, 0, stream>>>(w0b, Xp1, p2t, sidxg, swg, b0, Y0, gs0, gq0, 256, 512);
    k_gemmf<<<dim3(1, 512), 256, 0, stream>>>(w1b, Y0, b1, gamma0, beta0, gs0, gq0, Y1, gs1, gq1, 128, 256);
    k_out<<<dim3(16, 32), 256, 0, stream>>>(Y1, gs1, gq1, gamma1, beta1, out);
}

// Round 10
// 218.629 us; speedup vs baseline: 1.0797x; 1.0797x over previous
//
#include <hip/hip_runtime.h>
#include <stdint.h>

typedef unsigned short ushort_t;
typedef __attribute__((ext_vector_type(8))) __bf16 bf16x8;
typedef __attribute__((ext_vector_type(4))) float f32x4;

__device__ __forceinline__ float b2f(ushort_t u) {
    unsigned v = ((unsigned)u) << 16;
    float f;
    __builtin_memcpy(&f, &v, 4);
    return f;
}

// RNE f32->bf16 via compiler cast (v_cvt path on gfx950).
__device__ __forceinline__ ushort_t f2b(float f) {
    __bf16 h = (__bf16)f;
    return __builtin_bit_cast(ushort_t, h);
}

__device__ __forceinline__ void gl_lds16(const void* g, void* l) {
    __builtin_amdgcn_global_load_lds((const __attribute__((address_space(1))) void*)g,
                                     (__attribute__((address_space(3))) void*)l, 16, 0, 0);
}

// ---------------------------------------------------------------------------
// Fused preprocessing: w0/w1 bf16-cvt, sdat build, points2 transpose, and
// zeroing of the global BN-stat accumulators (re-zeroed every graph replay).
__global__ __launch_bounds__(256) void k_pre(const float* __restrict__ w0, ushort_t* __restrict__ w0b,
                                             const float* __restrict__ w1, ushort_t* __restrict__ w1b,
                                             const float* __restrict__ xyz2, float4* __restrict__ sdat,
                                             const float* __restrict__ points2, ushort_t* __restrict__ p2t,
                                             float* __restrict__ zb) {
    int bid = blockIdx.x;
    int t = threadIdx.x;
    if (bid < 512) {
        int i = bid * 256 + t;
        w0b[i] = f2b(w0[i]);
    } else if (bid < 640) {
        int i = (bid - 512) * 256 + t;
        w1b[i] = f2b(w1[i]);
    } else if (bid < 704) {
        int bb = bid - 640;
        int b = bb & 15, by = bb >> 4;
        int s = by * 256 + t;
        const float* x2 = xyz2 + (size_t)b * 3 * 1024;
        float x = x2[s], y = x2[1024 + s], z = x2[2048 + s];
        float4 v;
        v.x = x; v.y = y; v.z = z;
        v.w = __fadd_rn(__fadd_rn(__fmul_rn(x, x), __fmul_rn(y, y)), __fmul_rn(z, z));
        sdat[(size_t)b * 1024 + s] = v;
    } else if (bid < 960) {
        int bb = bid - 704;
        int b = bb & 15, sy = bb >> 4;
        int s = sy * 64 + (t & 63);
        int g = t >> 6;
        const float* src = points2 + (size_t)b * 128 * 1024 + s;
        ushort_t* dst = p2t + ((size_t)b * 1024 + s) * 128;
#pragma unroll
        for (int i = 0; i < 4; ++i) {
            int cp = i * 4 + g;
            ushort_t tmp[8];
#pragma unroll
            for (int k = 0; k < 8; ++k) tmp[k] = f2b(src[(size_t)(cp * 8 + k) * 1024]);
            *(uint4*)(dst + cp * 8) = *(const uint4*)tmp;
        }
    } else {
        // zero gs0[256] gq0[256] gs1[128] gq1[128]
        zb[t] = 0.f; zb[256 + t] = 0.f;
        if (t < 128) { zb[512 + t] = 0.f; zb[640 + t] = 0.f; }
    }
}

// ---------------------------------------------------------------------------
// 3-NN + build X [65536][512] bf16 (round-4 proven 47us version: 32 q/block,
// LDS-staged sdat, p1-hoist, sidx/sw aliased into dead sP region).
// Scan/merge math bit-identical to the verified version.
__global__ __launch_bounds__(256) void k_interp(const float* __restrict__ xyz1,
                                                const float4* __restrict__ sdat,
                                                const float* __restrict__ points1,
                                                const ushort_t* __restrict__ p2t,
                                                ushort_t* __restrict__ X) {
    int b = blockIdx.x;
    int n0 = blockIdx.y * 32;
    int t = threadIdx.x;
    int tq = t & 31;        // query within block
    int slice = t >> 5;     // 0..7
    int wave = t >> 6, lane = t & 63;

    __shared__ __align__(16) char sbuf[16384];  // sP during scan; sidx/sw after
    float4* sP = (float4*)sbuf;                 // 1024 float4 staged sdat[b]
    int*   sidx = (int*)sbuf;                   // 32*3 ints   (after scan)
    float* sw   = (float*)(sbuf + 384);         // 32*3 floats (after scan)
    __shared__ float sD[768];
    __shared__ int   sI[768];

    // stage sdat[b] -> LDS (wave w loads points [w*256, w*256+256))
    {
        const float4* src = sdat + (size_t)b * 1024;
#pragma unroll
        for (int c = 0; c < 4; ++c) {
            int p = wave * 256 + c * 64 + lane;
            gl_lds16(src + p, sbuf + p * 16);
        }
    }

    int n = n0 + tq;
    float x = xyz1[((size_t)b * 3 + 0) * 4096 + n];
    float y = xyz1[((size_t)b * 3 + 1) * 4096 + n];
    float z = xyz1[((size_t)b * 3 + 2) * 4096 + n];
    float s1 = __fadd_rn(__fadd_rn(__fmul_rn(x, x), __fmul_rn(y, y)), __fmul_rn(z, z));

    __syncthreads();   // staging complete (drains all vmcnt incl. gl_lds)

    // Issue points1 loads now: they ride out the scan in the vmem queue.
    const float* p1base = points1 + (size_t)b * 128 * 4096 + n0 + tq;
    float p1v[16];
#pragma unroll
    for (int i = 0; i < 2; ++i)
#pragma unroll
        for (int k = 0; k < 8; ++k)
            p1v[i * 8 + k] = p1base[(size_t)(((i * 8 + slice) * 8) + k) * 4096];

    float d0 = 1e30f, d1 = 1e30f, d2 = 1e30f;
    int i0 = 0, i1 = 0, i2 = 0;
    int sbeg = slice * 128;
    const float4* sdL = sP + sbeg;
#pragma unroll 8
    for (int s = 0; s < 128; ++s) {
        float4 v = sdL[s];
        float dot = fmaf(z, v.z, fmaf(y, v.y, __fmul_rn(x, v.x)));
        // fmaf(-2,dot,s1) == add(mul(-2,dot),s1) bit-exactly: *2 is exact.
        float d = __fadd_rn(fmaf(-2.0f, dot, s1), v.w);
        int si = sbeg + s;
        bool c0 = d < d0, c1 = d < d1, c2 = d < d2;
        // indices: identical logic to the verified version
        i2 = c1 ? i1 : (c2 ? si : i2);
        i1 = c0 ? i0 : (c1 ? si : i1);
        i0 = c0 ? si : i0;
        // distances: min/max forms select bit-identical values
        d2 = fminf(fmaxf(d, d1), d2);
        d1 = fminf(fmaxf(d, d0), d1);
        d0 = fminf(d, d0);
    }
    sD[t * 3 + 0] = d0; sD[t * 3 + 1] = d1; sD[t * 3 + 2] = d2;
    sI[t * 3 + 0] = i0; sI[t * 3 + 1] = i1; sI[t * 3 + 2] = i2;

    // points1 part: X[j][0:128] = bf16(points1[b][:, n]) (loads done above)
    {
        ushort_t* dstbase = X + (size_t)(b * 4096 + n0 + tq) * 512;
#pragma unroll
        for (int i = 0; i < 2; ++i) {
            int piece = i * 8 + slice;
            ushort_t tmp[8];
#pragma unroll
            for (int k = 0; k < 8; ++k) tmp[k] = f2b(p1v[i * 8 + k]);
            *(uint4*)(dstbase + piece * 8) = *(const uint4*)tmp;
        }
    }
    __syncthreads();   // scan + sD/sI complete; sP now dead

    // merge: threads t<32 pick global top-3 of 24 candidates by lex (d, idx).
    if (t < 32) {
        int sel0 = -1, sel1 = -1;
        float seld[3]; int seli[3];
#pragma unroll
        for (int r = 0; r < 3; ++r) {
            float bd = 1e38f; int bi = 1 << 30;
            for (int k = 0; k < 24; ++k) {
                int s3 = (k * 0xAAAB) >> 17;    // k/3 for k<=23
                int rank = k - s3 * 3;
                int base = (s3 * 32 + t) * 3 + rank;
                float cd = sD[base];
                int ci = sI[base];
                bool excl = (ci == sel0) | (ci == sel1);
                bool better = (!excl) & ((cd < bd) | ((cd == bd) & (ci < bi)));
                if (better) { bd = cd; bi = ci; }
            }
            seld[r] = bd; seli[r] = bi;
            if (r == 0) sel0 = bi; else if (r == 1) sel1 = bi;
        }
        float r0 = 1.0f / (seld[0] + 1e-8f);
        float r1 = 1.0f / (seld[1] + 1e-8f);
        float r2 = 1.0f / (seld[2] + 1e-8f);
        float rs = r0 + r1 + r2;
        sw[t * 3 + 0] = r0 / rs; sw[t * 3 + 1] = r1 / rs; sw[t * 3 + 2] = r2 / rs;
        sidx[t * 3 + 0] = seli[0]; sidx[t * 3 + 1] = seli[1]; sidx[t * 3 + 2] = seli[2];
    }
    __syncthreads();

    // gather: 32 queries x 48 pieces = 1536 items
#pragma unroll
    for (int i = 0; i < 6; ++i) {
        int idx = i * 256 + t;
        int q = idx / 48;
        int rem = idx - q * 48;
        int r = rem >> 4;
        int piece = rem & 15;
        int si = sidx[q * 3 + r] & 1023;   // clamp: defensive, free
        float wt = sw[q * 3 + r];
        const ushort_t* src = p2t + ((size_t)b * 1024 + si) * 128 + piece * 8;
        uint4 raw = *(const uint4*)src;
        ushort_t* e = (ushort_t*)&raw;
        ushort_t outv[8];
#pragma unroll
        for (int k = 0; k < 8; ++k) outv[k] = f2b(wt * b2f(e[k]));
        ushort_t* dst = X + (size_t)(b * 4096 + n0 + q) * 512 + 128 + r * 128 + piece * 8;
        *(uint4*)dst = *(const uint4*)outv;
    }
}

// ---------------------------------------------------------------------------
// GEMM0: BM=256 one block per j-tile (512 x 512thr, 8 waves = 4m x 2n) —
// X staged ONCE (round-5 proven structure) + T2 XOR swizzle (round-9 proven
// correct; kills the 6.7M-cycle stride-128B bank conflict) + global-accum
// BN stats (no k_bnfin launch). Gather-in-GEMM fusion ABANDONED: it doubled
// HBM traffic (FETCH 30->80, WRITE 49->100 MB, rounds 6/9).
__global__ __launch_bounds__(512, 4) void k_gemm(const ushort_t* __restrict__ A,
                                                 const ushort_t* __restrict__ Bt,
                                                 const float* __restrict__ bias,
                                                 ushort_t* __restrict__ Y,
                                                 float* __restrict__ gs,
                                                 float* __restrict__ gq,
                                                 int Mtot, int K) {
    __shared__ __align__(16) char smem[51200];
    ushort_t* As = (ushort_t*)smem;               // 256 x 64 bf16 = 32 KB, swizzled
    ushort_t* Bs = (ushort_t*)(smem + 32768);     // 128 x 64 bf16 = 16 KB, swizzled
    ushort_t* sY = (ushort_t*)smem;               // 128 x 136 epilogue (34816 B)
    float* red_s = (float*)(smem + 49152);        // 256 floats
    float* red_q = red_s + 256;                   // 256 floats

    int t = threadIdx.x;
    int j0 = blockIdx.x * 128;
    int wave = t >> 6, lane = t & 63;
    int wm = wave >> 1, wn = wave & 1;            // wm 0..3 (m), wn 0..1 (j)
    int l16 = lane & 15, quad = lane >> 4;
    int sw7 = l16 & 7;

    if (t < 256) { red_s[t] = 0.f; red_q[t] = 0.f; }

    f32x4 acc[4][4] = {};

    int nk = K >> 6;
    for (int kt = 0; kt < nk; ++kt) {
#pragma unroll
        for (int c = 0; c < 4; ++c) {
            int idx = c * 512 + t;
            int row = idx >> 3, kc = idx & 7;
            gl_lds16(A + (size_t)row * K + kt * 64 + ((kc ^ (row & 7)) * 8), As + idx * 8);
        }
#pragma unroll
        for (int c = 0; c < 2; ++c) {
            int idx = c * 512 + t;
            int row = idx >> 3, kc = idx & 7;
            gl_lds16(Bt + (size_t)(j0 + row) * K + kt * 64 + ((kc ^ (row & 7)) * 8), Bs + idx * 8);
        }
        __syncthreads();

#pragma unroll
        for (int kk = 0; kk < 2; ++kk) {
            bf16x8 af[4], bfr[4];
#pragma unroll
            for (int mi = 0; mi < 4; ++mi)
                af[mi] = *(const bf16x8*)(As + (wm * 64 + mi * 16 + l16) * 64 + (((kk * 4 + quad) ^ sw7) * 8));
#pragma unroll
            for (int ni = 0; ni < 4; ++ni)
                bfr[ni] = *(const bf16x8*)(Bs + (wn * 64 + ni * 16 + l16) * 64 + (((kk * 4 + quad) ^ sw7) * 8));
#pragma unroll
            for (int mi = 0; mi < 4; ++mi)
#pragma unroll
                for (int ni = 0; ni < 4; ++ni)
                    acc[mi][ni] = __builtin_amdgcn_mfma_f32_16x16x32_bf16(af[mi], bfr[ni], acc[mi][ni], 0, 0, 0);
        }
        __syncthreads();
    }

    // epilogue: two m-halves through the 128x136 sY staging region
#pragma unroll
    for (int h = 0; h < 2; ++h) {
        if ((wm >> 1) == h) {
#pragma unroll
            for (int mi = 0; mi < 4; ++mi) {
                int obase = wm * 64 + mi * 16 + quad * 4;    // absolute channel
                int ocol = obase - h * 128;                  // 0..124 in half
                float bv[4];
#pragma unroll
                for (int r = 0; r < 4; ++r) bv[r] = bias[obase + r];
                float sr[4] = {0.f, 0.f, 0.f, 0.f}, qr[4] = {0.f, 0.f, 0.f, 0.f};
#pragma unroll
                for (int ni = 0; ni < 4; ++ni) {
                    int j_local = wn * 64 + ni * 16 + l16;
                    ushort4 pk;
                    float v0 = acc[mi][ni][0] + bv[0];
                    float v1 = acc[mi][ni][1] + bv[1];
                    float v2 = acc[mi][ni][2] + bv[2];
                    float v3 = acc[mi][ni][3] + bv[3];
                    pk.x = f2b(v0); pk.y = f2b(v1); pk.z = f2b(v2); pk.w = f2b(v3);
                    sr[0] += v0; qr[0] += v0 * v0;
                    sr[1] += v1; qr[1] += v1 * v1;
                    sr[2] += v2; qr[2] += v2 * v2;
                    sr[3] += v3; qr[3] += v3 * v3;
                    *(ushort4*)(sY + j_local * 136 + ocol) = pk;
                }
#pragma unroll
                for (int r = 0; r < 4; ++r) {
                    float s = sr[r], q = qr[r];
                    s += __shfl_xor(s, 1); s += __shfl_xor(s, 2);
                    s += __shfl_xor(s, 4); s += __shfl_xor(s, 8);
                    q += __shfl_xor(q, 1); q += __shfl_xor(q, 2);
                    q += __shfl_xor(q, 4); q += __shfl_xor(q, 8);
                    if (l16 == 0) {
                        atomicAdd(&red_s[obase + r], s);
                        atomicAdd(&red_q[obase + r], q);
                    }
                }
            }
        }
        __syncthreads();
#pragma unroll
        for (int rep = 0; rep < 4; ++rep) {
            int idx = rep * 512 + t;
            int jl = idx >> 4;
            int o8 = idx & 15;
            uint4 vv = *(const uint4*)(sY + jl * 136 + o8 * 8);
            *(uint4*)(Y + (size_t)(j0 + jl) * Mtot + h * 128 + o8 * 8) = vv;
        }
        __syncthreads();
    }
    if (t < 256) {
        atomicAdd(&gs[t], red_s[t]);
        atomicAdd(&gq[t], red_q[t]);
    }
}

// ---------------------------------------------------------------------------
// GEMM1: fused BN0 finalize in prologue + BN0+ReLU at B staging + T2 swizzle
// (round-9 proven). Stats to gs1/gq1 accumulators.
__global__ __launch_bounds__(256) void k_gemmf(const ushort_t* __restrict__ A,
                                               const ushort_t* __restrict__ Y0,
                                               const float* __restrict__ bias,
                                               const float* __restrict__ gamma0,
                                               const float* __restrict__ beta0,
                                               const float* __restrict__ gs0,
                                               const float* __restrict__ gq0,
                                               ushort_t* __restrict__ Y,
                                               float* __restrict__ gs1,
                                               float* __restrict__ gq1,
                                               int Mtot, int K) {
    __shared__ __align__(16) char smem[35840];
    ushort_t* As = (ushort_t*)smem;               // 128 x 64, swizzled
    ushort_t* Bs = (ushort_t*)(smem + 16384);     // 128 x 64, swizzled
    float* sa = (float*)(smem + 32768);           // 256 floats
    float* sb = (float*)(smem + 33792);           // 256 floats
    ushort_t* sY = (ushort_t*)smem;               // epilogue reuse
    float* red_s = (float*)(smem + 34816);
    float* red_q = red_s + 128;

    int t = threadIdx.x;
    int m0 = blockIdx.x * 128;
    int j0 = blockIdx.y * 128;
    int wave = t >> 6, lane = t & 63;
    int wm = wave >> 1, wn = wave & 1;
    int l16 = lane & 15, quad = lane >> 4;
    int sw7 = l16 & 7;

    // BN0 finalize (identical math to the former k_bnfin)
    {
        float s = gs0[t], q = gq0[t];
        float mean = s * (1.0f / 65536.0f);
        float var = q * (1.0f / 65536.0f) - mean * mean;
        float sc = gamma0[t] / sqrtf(var + 1e-5f);
        sa[t] = sc;
        sb[t] = beta0[t] - mean * sc;
    }
    if (t < 128) { red_s[t] = 0.f; red_q[t] = 0.f; }
    __syncthreads();

    f32x4 acc[4][4] = {};

    int nk = K >> 6;
    for (int kt = 0; kt < nk; ++kt) {
#pragma unroll
        for (int c = 0; c < 4; ++c) {
            int idx = c * 256 + t;
            int row = idx >> 3, kc = idx & 7;
            gl_lds16(A + (size_t)(m0 + row) * K + kt * 64 + ((kc ^ (row & 7)) * 8), As + idx * 8);
        }
#pragma unroll
        for (int c = 0; c < 4; ++c) {
            int idx = c * 256 + t;
            int row = idx >> 3, kc = idx & 7;
            int cbase = kt * 64 + kc * 8;
            uint4 raw = *(const uint4*)(Y0 + (size_t)(j0 + row) * K + cbase);
            ushort_t* e = (ushort_t*)&raw;
            ushort_t outv[8];
#pragma unroll
            for (int k = 0; k < 8; ++k) {
                float v = fmaxf(sa[cbase + k] * b2f(e[k]) + sb[cbase + k], 0.f);
                outv[k] = f2b(v);
            }
            *(uint4*)(Bs + row * 64 + ((kc ^ (row & 7)) * 8)) = *(const uint4*)outv;
        }
        __syncthreads();

#pragma unroll
        for (int kk = 0; kk < 2; ++kk) {
            bf16x8 af[4], bfr[4];
#pragma unroll
            for (int mi = 0; mi < 4; ++mi)
                af[mi] = *(const bf16x8*)(As + (wm * 64 + mi * 16 + l16) * 64 + (((kk * 4 + quad) ^ sw7) * 8));
#pragma unroll
            for (int ni = 0; ni < 4; ++ni)
                bfr[ni] = *(const bf16x8*)(Bs + (wn * 64 + ni * 16 + l16) * 64 + (((kk * 4 + quad) ^ sw7) * 8));
#pragma unroll
            for (int mi = 0; mi < 4; ++mi)
#pragma unroll
                for (int ni = 0; ni < 4; ++ni)
                    acc[mi][ni] = __builtin_amdgcn_mfma_f32_16x16x32_bf16(af[mi], bfr[ni], acc[mi][ni], 0, 0, 0);
        }
        __syncthreads();
    }

#pragma unroll
    for (int mi = 0; mi < 4; ++mi) {
        int obase = wm * 64 + mi * 16 + quad * 4;
        float bv[4];
#pragma unroll
        for (int r = 0; r < 4; ++r) bv[r] = bias[m0 + obase + r];
        float sr[4] = {0.f, 0.f, 0.f, 0.f}, qr[4] = {0.f, 0.f, 0.f, 0.f};
#pragma unroll
        for (int ni = 0; ni < 4; ++ni) {
            int j_local = wn * 64 + ni * 16 + l16;
            ushort4 pk;
            float v0 = acc[mi][ni][0] + bv[0];
            float v1 = acc[mi][ni][1] + bv[1];
            float v2 = acc[mi][ni][2] + bv[2];
            float v3 = acc[mi][ni][3] + bv[3];
            pk.x = f2b(v0); pk.y = f2b(v1); pk.z = f2b(v2); pk.w = f2b(v3);
            sr[0] += v0; qr[0] += v0 * v0;
            sr[1] += v1; qr[1] += v1 * v1;
            sr[2] += v2; qr[2] += v2 * v2;
            sr[3] += v3; qr[3] += v3 * v3;
            *(ushort4*)(sY + j_local * 136 + obase) = pk;
        }
#pragma unroll
        for (int r = 0; r < 4; ++r) {
            float s = sr[r], q = qr[r];
            s += __shfl_xor(s, 1); s += __shfl_xor(s, 2);
            s += __shfl_xor(s, 4); s += __shfl_xor(s, 8);
            q += __shfl_xor(q, 1); q += __shfl_xor(q, 2);
            q += __shfl_xor(q, 4); q += __shfl_xor(q, 8);
            if (l16 == 0) {
                atomicAdd(&red_s[obase + r], s);
                atomicAdd(&red_q[obase + r], q);
            }
        }
    }
    __syncthreads();

#pragma unroll
    for (int rep = 0; rep < 8; ++rep) {
        int idx = rep * 256 + t;
        int jl = idx >> 4;
        int o8 = idx & 15;
        uint4 vv = *(const uint4*)(sY + jl * 136 + o8 * 8);
        *(uint4*)(Y + (size_t)(j0 + jl) * Mtot + m0 + o8 * 8) = vv;
    }
    if (t < 128) {
        atomicAdd(&gs1[m0 + t], red_s[t]);
        atomicAdd(&gq1[m0 + t], red_q[t]);
    }
}

// ---------------------------------------------------------------------------
// Output: fused BN1 finalize in prologue + BN1+ReLU + fp32 transpose-store.
__global__ __launch_bounds__(256) void k_out(const ushort_t* __restrict__ Y1,
                                             const float* __restrict__ gs1,
                                             const float* __restrict__ gq1,
                                             const float* __restrict__ gamma1,
                                             const float* __restrict__ beta1,
                                             float* __restrict__ out) {
    __shared__ float sa[128], sb[128];
    int t = threadIdx.x;
    if (t < 128) {
        float s = gs1[t], q = gq1[t];
        float mean = s * (1.0f / 65536.0f);
        float var = q * (1.0f / 65536.0f) - mean * mean;
        float sc = gamma1[t] / sqrtf(var + 1e-5f);
        sa[t] = sc;
        sb[t] = beta1[t] - mean * sc;
    }
    __syncthreads();
    int b = blockIdx.x;
    int nl = t & 127;
    int half = t >> 7;
    int n = blockIdx.y * 128 + nl;
    const uint4* src = (const uint4*)(Y1 + (size_t)(b * 4096 + n) * 128);
    float* dst = out + (size_t)b * 128 * 4096 + n;
    uint4 raw[8];
#pragma unroll
    for (int p = 0; p < 8; ++p) raw[p] = src[half * 8 + p];
    const ushort_t* e = (const ushort_t*)raw;
#pragma unroll
    for (int c = 0; c < 64; ++c) {
        int ch = half * 64 + c;
        float v = b2f(e[c]);
        v = fmaxf(sa[ch] * v + sb[ch], 0.f);
        dst[(size_t)ch * 4096] = v;
    }
}

// ---------------------------------------------------------------------------
extern "C" void kernel_launch(void* const* d_in, const int* in_sizes, int n_in,
                              void* d_out, int out_size, void* d_ws, size_t ws_size,
                              hipStream_t stream) {
    const float* xyz1    = (const float*)d_in[0];
    const float* xyz2    = (const float*)d_in[1];
    const float* points1 = (const float*)d_in[2];
    const float* points2 = (const float*)d_in[3];
    const float* w0      = (const float*)d_in[4];
    const float* b0      = (const float*)d_in[5];
    const float* gamma0  = (const float*)d_in[6];
    const float* beta0   = (const float*)d_in[7];
    const float* w1      = (const float*)d_in[8];
    const float* b1      = (const float*)d_in[9];
    const float* gamma1  = (const float*)d_in[10];
    const float* beta1   = (const float*)d_in[11];
    float* out = (float*)d_out;

    char* ws = (char*)d_ws;
    const size_t OFF_X    = 0;                       // 67108864
    const size_t OFF_Y0   = 67108864;                // 33554432
    const size_t OFF_Y1   = 100663296;               // 16777216
    const size_t OFF_P2T  = 117440512;               // 4194304
    const size_t OFF_W0B  = 121634816;               // 262144
    const size_t OFF_W1B  = 121896960;               // 65536
    const size_t OFF_AB   = 121962496;               // 3072 (global stat accum)
    const size_t OFF_SDAT = 121965568;               // 262144

    ushort_t* X    = (ushort_t*)(ws + OFF_X);
    ushort_t* Y0   = (ushort_t*)(ws + OFF_Y0);
    ushort_t* Y1   = (ushort_t*)(ws + OFF_Y1);
    ushort_t* p2t  = (ushort_t*)(ws + OFF_P2T);
    ushort_t* w0b  = (ushort_t*)(ws + OFF_W0B);
    ushort_t* w1b  = (ushort_t*)(ws + OFF_W1B);
    float* ab      = (float*)(ws + OFF_AB);
    float4* sdat   = (float4*)(ws + OFF_SDAT);
    float* gs0 = ab;        float* gq0 = ab + 256;
    float* gs1 = ab + 512;  float* gq1 = ab + 640;

    k_pre<<<961, 256, 0, stream>>>(w0, w0b, w1, w1b, xyz2, sdat, points2, p2t, ab);
    k_interp<<<dim3(16, 128), 256, 0, stream>>>(xyz1, sdat, points1, p2t, X);
    k_gemm<<<512, 512, 0, stream>>>(w0b, X, b0, Y0, gs0, gq0, 256, 512);
    k_gemmf<<<dim3(1, 512), 256, 0, stream>>>(w1b, Y0, b1, gamma0, beta0, gs0, gq0, Y1, gs1, gq1, 128, 256);
    k_out<<<dim3(16, 32), 256, 0, stream>>>(Y1, gs1, gq1, gamma1, beta1, out);
}

// Round 11
// 217.207 us; speedup vs baseline: 1.0867x; 1.0065x over previous
//
#include <hip/hip_runtime.h>
#include <stdint.h>

typedef unsigned short ushort_t;
typedef __attribute__((ext_vector_type(8))) __bf16 bf16x8;
typedef __attribute__((ext_vector_type(4))) float f32x4;

__device__ __forceinline__ float b2f(ushort_t u) {
    unsigned v = ((unsigned)u) << 16;
    float f;
    __builtin_memcpy(&f, &v, 4);
    return f;
}

// RNE f32->bf16 via compiler cast (v_cvt path on gfx950).
__device__ __forceinline__ ushort_t f2b(float f) {
    __bf16 h = (__bf16)f;
    return __builtin_bit_cast(ushort_t, h);
}

__device__ __forceinline__ void gl_lds16(const void* g, void* l) {
    __builtin_amdgcn_global_load_lds((const __attribute__((address_space(1))) void*)g,
                                     (__attribute__((address_space(3))) void*)l, 16, 0, 0);
}

// ---------------------------------------------------------------------------
// Fused preprocessing: w0/w1 bf16-cvt, sdat build, points2 transpose, and
// zeroing of the 8-way-spread global BN-stat accumulators.
__global__ __launch_bounds__(256) void k_pre(const float* __restrict__ w0, ushort_t* __restrict__ w0b,
                                             const float* __restrict__ w1, ushort_t* __restrict__ w1b,
                                             const float* __restrict__ xyz2, float4* __restrict__ sdat,
                                             const float* __restrict__ points2, ushort_t* __restrict__ p2t,
                                             float* __restrict__ zb) {
    int bid = blockIdx.x;
    int t = threadIdx.x;
    if (bid < 512) {
        int i = bid * 256 + t;
        w0b[i] = f2b(w0[i]);
    } else if (bid < 640) {
        int i = (bid - 512) * 256 + t;
        w1b[i] = f2b(w1[i]);
    } else if (bid < 704) {
        int bb = bid - 640;
        int b = bb & 15, by = bb >> 4;
        int s = by * 256 + t;
        const float* x2 = xyz2 + (size_t)b * 3 * 1024;
        float x = x2[s], y = x2[1024 + s], z = x2[2048 + s];
        float4 v;
        v.x = x; v.y = y; v.z = z;
        v.w = __fadd_rn(__fadd_rn(__fmul_rn(x, x), __fmul_rn(y, y)), __fmul_rn(z, z));
        sdat[(size_t)b * 1024 + s] = v;
    } else if (bid < 960) {
        int bb = bid - 704;
        int b = bb & 15, sy = bb >> 4;
        int s = sy * 64 + (t & 63);
        int g = t >> 6;
        const float* src = points2 + (size_t)b * 128 * 1024 + s;
        ushort_t* dst = p2t + ((size_t)b * 1024 + s) * 128;
#pragma unroll
        for (int i = 0; i < 4; ++i) {
            int cp = i * 4 + g;
            ushort_t tmp[8];
#pragma unroll
            for (int k = 0; k < 8; ++k) tmp[k] = f2b(src[(size_t)(cp * 8 + k) * 1024]);
            *(uint4*)(dst + cp * 8) = *(const uint4*)tmp;
        }
    } else {
        // zero 8-way stat copies: gs0[8][256] gq0[8][256] gs1[8][128] gq1[8][128]
        for (int i = t; i < 6144; i += 256) zb[i] = 0.f;
    }
}

// ---------------------------------------------------------------------------
// 3-NN + build X [65536][512] bf16 (proven 46-48us version: 32 q/block,
// LDS-staged sdat, p1-hoist, sidx/sw aliased into dead sP region).
// Scan/merge math bit-identical to the verified version.
__global__ __launch_bounds__(256) void k_interp(const float* __restrict__ xyz1,
                                                const float4* __restrict__ sdat,
                                                const float* __restrict__ points1,
                                                const ushort_t* __restrict__ p2t,
                                                ushort_t* __restrict__ X) {
    int b = blockIdx.x;
    int n0 = blockIdx.y * 32;
    int t = threadIdx.x;
    int tq = t & 31;        // query within block
    int slice = t >> 5;     // 0..7
    int wave = t >> 6, lane = t & 63;

    __shared__ __align__(16) char sbuf[16384];  // sP during scan; sidx/sw after
    float4* sP = (float4*)sbuf;                 // 1024 float4 staged sdat[b]
    int*   sidx = (int*)sbuf;                   // 32*3 ints   (after scan)
    float* sw   = (float*)(sbuf + 384);         // 32*3 floats (after scan)
    __shared__ float sD[768];
    __shared__ int   sI[768];

    // stage sdat[b] -> LDS (wave w loads points [w*256, w*256+256))
    {
        const float4* src = sdat + (size_t)b * 1024;
#pragma unroll
        for (int c = 0; c < 4; ++c) {
            int p = wave * 256 + c * 64 + lane;
            gl_lds16(src + p, sbuf + p * 16);
        }
    }

    int n = n0 + tq;
    float x = xyz1[((size_t)b * 3 + 0) * 4096 + n];
    float y = xyz1[((size_t)b * 3 + 1) * 4096 + n];
    float z = xyz1[((size_t)b * 3 + 2) * 4096 + n];
    float s1 = __fadd_rn(__fadd_rn(__fmul_rn(x, x), __fmul_rn(y, y)), __fmul_rn(z, z));

    __syncthreads();   // staging complete (drains all vmcnt incl. gl_lds)

    // Issue points1 loads now: they ride out the scan in the vmem queue.
    const float* p1base = points1 + (size_t)b * 128 * 4096 + n0 + tq;
    float p1v[16];
#pragma unroll
    for (int i = 0; i < 2; ++i)
#pragma unroll
        for (int k = 0; k < 8; ++k)
            p1v[i * 8 + k] = p1base[(size_t)(((i * 8 + slice) * 8) + k) * 4096];

    float d0 = 1e30f, d1 = 1e30f, d2 = 1e30f;
    int i0 = 0, i1 = 0, i2 = 0;
    int sbeg = slice * 128;
    const float4* sdL = sP + sbeg;
#pragma unroll 8
    for (int s = 0; s < 128; ++s) {
        float4 v = sdL[s];
        float dot = fmaf(z, v.z, fmaf(y, v.y, __fmul_rn(x, v.x)));
        // fmaf(-2,dot,s1) == add(mul(-2,dot),s1) bit-exactly: *2 is exact.
        float d = __fadd_rn(fmaf(-2.0f, dot, s1), v.w);
        int si = sbeg + s;
        bool c0 = d < d0, c1 = d < d1, c2 = d < d2;
        // indices: identical logic to the verified version
        i2 = c1 ? i1 : (c2 ? si : i2);
        i1 = c0 ? i0 : (c1 ? si : i1);
        i0 = c0 ? si : i0;
        // distances: min/max forms select bit-identical values
        d2 = fminf(fmaxf(d, d1), d2);
        d1 = fminf(fmaxf(d, d0), d1);
        d0 = fminf(d, d0);
    }
    sD[t * 3 + 0] = d0; sD[t * 3 + 1] = d1; sD[t * 3 + 2] = d2;
    sI[t * 3 + 0] = i0; sI[t * 3 + 1] = i1; sI[t * 3 + 2] = i2;

    // points1 part: X[j][0:128] = bf16(points1[b][:, n]) (loads done above)
    {
        ushort_t* dstbase = X + (size_t)(b * 4096 + n0 + tq) * 512;
#pragma unroll
        for (int i = 0; i < 2; ++i) {
            int piece = i * 8 + slice;
            ushort_t tmp[8];
#pragma unroll
            for (int k = 0; k < 8; ++k) tmp[k] = f2b(p1v[i * 8 + k]);
            *(uint4*)(dstbase + piece * 8) = *(const uint4*)tmp;
        }
    }
    __syncthreads();   // scan + sD/sI complete; sP now dead

    // merge: threads t<32 pick global top-3 of 24 candidates by lex (d, idx).
    if (t < 32) {
        int sel0 = -1, sel1 = -1;
        float seld[3]; int seli[3];
#pragma unroll
        for (int r = 0; r < 3; ++r) {
            float bd = 1e38f; int bi = 1 << 30;
            for (int k = 0; k < 24; ++k) {
                int s3 = (k * 0xAAAB) >> 17;    // k/3 for k<=23
                int rank = k - s3 * 3;
                int base = (s3 * 32 + t) * 3 + rank;
                float cd = sD[base];
                int ci = sI[base];
                bool excl = (ci == sel0) | (ci == sel1);
                bool better = (!excl) & ((cd < bd) | ((cd == bd) & (ci < bi)));
                if (better) { bd = cd; bi = ci; }
            }
            seld[r] = bd; seli[r] = bi;
            if (r == 0) sel0 = bi; else if (r == 1) sel1 = bi;
        }
        float r0 = 1.0f / (seld[0] + 1e-8f);
        float r1 = 1.0f / (seld[1] + 1e-8f);
        float r2 = 1.0f / (seld[2] + 1e-8f);
        float rs = r0 + r1 + r2;
        sw[t * 3 + 0] = r0 / rs; sw[t * 3 + 1] = r1 / rs; sw[t * 3 + 2] = r2 / rs;
        sidx[t * 3 + 0] = seli[0]; sidx[t * 3 + 1] = seli[1]; sidx[t * 3 + 2] = seli[2];
    }
    __syncthreads();

    // gather: 32 queries x 48 pieces = 1536 items
#pragma unroll
    for (int i = 0; i < 6; ++i) {
        int idx = i * 256 + t;
        int q = idx / 48;
        int rem = idx - q * 48;
        int r = rem >> 4;
        int piece = rem & 15;
        int si = sidx[q * 3 + r] & 1023;   // clamp: defensive, free
        float wt = sw[q * 3 + r];
        const ushort_t* src = p2t + ((size_t)b * 1024 + si) * 128 + piece * 8;
        uint4 raw = *(const uint4*)src;
        ushort_t* e = (ushort_t*)&raw;
        ushort_t outv[8];
#pragma unroll
        for (int k = 0; k < 8; ++k) outv[k] = f2b(wt * b2f(e[k]));
        ushort_t* dst = X + (size_t)(b * 4096 + n0 + q) * 512 + 128 + r * 128 + piece * 8;
        *(uint4*)dst = *(const uint4*)outv;
    }
}

// ---------------------------------------------------------------------------
// GEMM0: BM=256 x BN=64 tile, 1024 blocks x 512 thr (8 waves = 4m x 2n,
// acc[4][2]). X read once (BM spans full M); LDS 43KB -> 3 blocks/CU (vs 2
// before: the 2-barrier staging is hidden by cross-block overlap, m114/m233).
// T2 XOR swizzle kept (17x conflict kill, round-9 measured). Stats go to
// 8-way-spread global accumulators (copy = blockIdx.x&7) to cut the 512-way
// atomic contention tail.
__global__ __launch_bounds__(512, 6) void k_gemm(const ushort_t* __restrict__ A,
                                                 const ushort_t* __restrict__ Bt,
                                                 const float* __restrict__ bias,
                                                 ushort_t* __restrict__ Y,
                                                 float* __restrict__ gs,
                                                 float* __restrict__ gq,
                                                 int Mtot, int K) {
    __shared__ __align__(16) char smem[43008];
    ushort_t* As = (ushort_t*)smem;               // 256 x 64 bf16 = 32 KB, swizzled
    ushort_t* Bs = (ushort_t*)(smem + 32768);     // 64 x 64 bf16 = 8 KB, swizzled
    ushort_t* sY = (ushort_t*)smem;               // 64 x 264 epilogue (33792 B)
    float* red_s = (float*)(smem + 40960);        // 256 floats
    float* red_q = red_s + 256;                   // 256 floats

    int t = threadIdx.x;
    int j0 = blockIdx.x * 64;
    int wave = t >> 6, lane = t & 63;
    int wm = wave >> 1, wn = wave & 1;            // wm 0..3 (m), wn 0..1 (j)
    int l16 = lane & 15, quad = lane >> 4;
    int sw7 = l16 & 7;

    if (t < 256) { red_s[t] = 0.f; red_q[t] = 0.f; }

    f32x4 acc[4][2] = {};

    int nk = K >> 6;
    for (int kt = 0; kt < nk; ++kt) {
#pragma unroll
        for (int c = 0; c < 4; ++c) {
            int idx = c * 512 + t;
            int row = idx >> 3, kc = idx & 7;
            gl_lds16(A + (size_t)row * K + kt * 64 + ((kc ^ (row & 7)) * 8), As + idx * 8);
        }
        {
            int idx = t;                           // 512 chunks exactly
            int row = idx >> 3, kc = idx & 7;
            gl_lds16(Bt + (size_t)(j0 + row) * K + kt * 64 + ((kc ^ (row & 7)) * 8), Bs + idx * 8);
        }
        __syncthreads();

#pragma unroll
        for (int kk = 0; kk < 2; ++kk) {
            bf16x8 af[4], bfr[2];
#pragma unroll
            for (int mi = 0; mi < 4; ++mi)
                af[mi] = *(const bf16x8*)(As + (wm * 64 + mi * 16 + l16) * 64 + (((kk * 4 + quad) ^ sw7) * 8));
#pragma unroll
            for (int ni = 0; ni < 2; ++ni)
                bfr[ni] = *(const bf16x8*)(Bs + (wn * 32 + ni * 16 + l16) * 64 + (((kk * 4 + quad) ^ sw7) * 8));
#pragma unroll
            for (int mi = 0; mi < 4; ++mi)
#pragma unroll
                for (int ni = 0; ni < 2; ++ni)
                    acc[mi][ni] = __builtin_amdgcn_mfma_f32_16x16x32_bf16(af[mi], bfr[ni], acc[mi][ni], 0, 0, 0);
        }
        __syncthreads();
    }

    // epilogue: full 64j x 256ch tile through sY (single pass)
#pragma unroll
    for (int mi = 0; mi < 4; ++mi) {
        int obase = wm * 64 + mi * 16 + quad * 4;    // channel 0..255
        float bv[4];
#pragma unroll
        for (int r = 0; r < 4; ++r) bv[r] = bias[obase + r];
        float sr[4] = {0.f, 0.f, 0.f, 0.f}, qr[4] = {0.f, 0.f, 0.f, 0.f};
#pragma unroll
        for (int ni = 0; ni < 2; ++ni) {
            int j_local = wn * 32 + ni * 16 + l16;
            ushort4 pk;
            float v0 = acc[mi][ni][0] + bv[0];
            float v1 = acc[mi][ni][1] + bv[1];
            float v2 = acc[mi][ni][2] + bv[2];
            float v3 = acc[mi][ni][3] + bv[3];
            pk.x = f2b(v0); pk.y = f2b(v1); pk.z = f2b(v2); pk.w = f2b(v3);
            sr[0] += v0; qr[0] += v0 * v0;
            sr[1] += v1; qr[1] += v1 * v1;
            sr[2] += v2; qr[2] += v2 * v2;
            sr[3] += v3; qr[3] += v3 * v3;
            *(ushort4*)(sY + j_local * 264 + obase) = pk;
        }
#pragma unroll
        for (int r = 0; r < 4; ++r) {
            float s = sr[r], q = qr[r];
            s += __shfl_xor(s, 1); s += __shfl_xor(s, 2);
            s += __shfl_xor(s, 4); s += __shfl_xor(s, 8);
            q += __shfl_xor(q, 1); q += __shfl_xor(q, 2);
            q += __shfl_xor(q, 4); q += __shfl_xor(q, 8);
            if (l16 == 0) {
                atomicAdd(&red_s[obase + r], s);
                atomicAdd(&red_q[obase + r], q);
            }
        }
    }
    __syncthreads();

#pragma unroll
    for (int rep = 0; rep < 4; ++rep) {
        int idx = rep * 512 + t;
        int jl = idx >> 5;
        int o8 = idx & 31;
        uint4 vv = *(const uint4*)(sY + jl * 264 + o8 * 8);
        *(uint4*)(Y + (size_t)(j0 + jl) * Mtot + o8 * 8) = vv;
    }
    if (t < 256) {
        int cp = blockIdx.x & 7;
        atomicAdd(&gs[cp * 256 + t], red_s[t]);
        atomicAdd(&gq[cp * 256 + t], red_q[t]);
    }
}

// ---------------------------------------------------------------------------
// GEMM1: BM=128 x BN=64, 1024 blocks x 256 thr (4 waves = 2m x 2n, acc[4][2],
// LDS 27.6KB -> 5 blocks/CU). Fused BN0 finalize in prologue (sums 8 stat
// copies) + BN0+ReLU at B staging + T2 swizzle.
__global__ __launch_bounds__(256, 4) void k_gemmf(const ushort_t* __restrict__ A,
                                                  const ushort_t* __restrict__ Y0,
                                                  const float* __restrict__ bias,
                                                  const float* __restrict__ gamma0,
                                                  const float* __restrict__ beta0,
                                                  const float* __restrict__ gs0,
                                                  const float* __restrict__ gq0,
                                                  ushort_t* __restrict__ Y,
                                                  float* __restrict__ gs1,
                                                  float* __restrict__ gq1,
                                                  int Mtot, int K) {
    __shared__ __align__(16) char smem[27648];
    ushort_t* As = (ushort_t*)smem;               // 128 x 64 = 16 KB, swizzled
    ushort_t* Bs = (ushort_t*)(smem + 16384);     // 64 x 64 = 8 KB, swizzled
    ushort_t* sY = (ushort_t*)smem;               // 64 x 136 epilogue (17408 B)
    float* sa = (float*)(smem + 24576);           // 256 floats
    float* sb = (float*)(smem + 25600);           // 256 floats
    float* red_s = (float*)(smem + 26624);        // 128 floats
    float* red_q = red_s + 128;                   // 128 floats

    int t = threadIdx.x;
    int j0 = blockIdx.x * 64;
    int wave = t >> 6, lane = t & 63;
    int wm = wave >> 1, wn = wave & 1;
    int l16 = lane & 15, quad = lane >> 4;
    int sw7 = l16 & 7;

    // BN0 finalize (sum 8 spread copies; identical math to former k_bnfin)
    {
        float s = 0.f, q = 0.f;
#pragma unroll
        for (int k = 0; k < 8; ++k) { s += gs0[k * 256 + t]; q += gq0[k * 256 + t]; }
        float mean = s * (1.0f / 65536.0f);
        float var = q * (1.0f / 65536.0f) - mean * mean;
        float sc = gamma0[t] / sqrtf(var + 1e-5f);
        sa[t] = sc;
        sb[t] = beta0[t] - mean * sc;
    }
    if (t < 128) { red_s[t] = 0.f; red_q[t] = 0.f; }
    __syncthreads();

    f32x4 acc[4][2] = {};

    int nk = K >> 6;
    for (int kt = 0; kt < nk; ++kt) {
#pragma unroll
        for (int c = 0; c < 4; ++c) {
            int idx = c * 256 + t;
            int row = idx >> 3, kc = idx & 7;
            gl_lds16(A + (size_t)row * K + kt * 64 + ((kc ^ (row & 7)) * 8), As + idx * 8);
        }
#pragma unroll
        for (int c = 0; c < 2; ++c) {
            int idx = c * 256 + t;
            int row = idx >> 3, kc = idx & 7;
            int cbase = kt * 64 + kc * 8;
            uint4 raw = *(const uint4*)(Y0 + (size_t)(j0 + row) * K + cbase);
            ushort_t* e = (ushort_t*)&raw;
            ushort_t outv[8];
#pragma unroll
            for (int k = 0; k < 8; ++k) {
                float v = fmaxf(sa[cbase + k] * b2f(e[k]) + sb[cbase + k], 0.f);
                outv[k] = f2b(v);
            }
            *(uint4*)(Bs + row * 64 + ((kc ^ (row & 7)) * 8)) = *(const uint4*)outv;
        }
        __syncthreads();

#pragma unroll
        for (int kk = 0; kk < 2; ++kk) {
            bf16x8 af[4], bfr[2];
#pragma unroll
            for (int mi = 0; mi < 4; ++mi)
                af[mi] = *(const bf16x8*)(As + (wm * 64 + mi * 16 + l16) * 64 + (((kk * 4 + quad) ^ sw7) * 8));
#pragma unroll
            for (int ni = 0; ni < 2; ++ni)
                bfr[ni] = *(const bf16x8*)(Bs + (wn * 32 + ni * 16 + l16) * 64 + (((kk * 4 + quad) ^ sw7) * 8));
#pragma unroll
            for (int mi = 0; mi < 4; ++mi)
#pragma unroll
                for (int ni = 0; ni < 2; ++ni)
                    acc[mi][ni] = __builtin_amdgcn_mfma_f32_16x16x32_bf16(af[mi], bfr[ni], acc[mi][ni], 0, 0, 0);
        }
        __syncthreads();
    }

#pragma unroll
    for (int mi = 0; mi < 4; ++mi) {
        int obase = wm * 64 + mi * 16 + quad * 4;    // channel 0..127
        float bv[4];
#pragma unroll
        for (int r = 0; r < 4; ++r) bv[r] = bias[obase + r];
        float sr[4] = {0.f, 0.f, 0.f, 0.f}, qr[4] = {0.f, 0.f, 0.f, 0.f};
#pragma unroll
        for (int ni = 0; ni < 2; ++ni) {
            int j_local = wn * 32 + ni * 16 + l16;
            ushort4 pk;
            float v0 = acc[mi][ni][0] + bv[0];
            float v1 = acc[mi][ni][1] + bv[1];
            float v2 = acc[mi][ni][2] + bv[2];
            float v3 = acc[mi][ni][3] + bv[3];
            pk.x = f2b(v0); pk.y = f2b(v1); pk.z = f2b(v2); pk.w = f2b(v3);
            sr[0] += v0; qr[0] += v0 * v0;
            sr[1] += v1; qr[1] += v1 * v1;
            sr[2] += v2; qr[2] += v2 * v2;
            sr[3] += v3; qr[3] += v3 * v3;
            *(ushort4*)(sY + j_local * 136 + obase) = pk;
        }
#pragma unroll
        for (int r = 0; r < 4; ++r) {
            float s = sr[r], q = qr[r];
            s += __shfl_xor(s, 1); s += __shfl_xor(s, 2);
            s += __shfl_xor(s, 4); s += __shfl_xor(s, 8);
            q += __shfl_xor(q, 1); q += __shfl_xor(q, 2);
            q += __shfl_xor(q, 4); q += __shfl_xor(q, 8);
            if (l16 == 0) {
                atomicAdd(&red_s[obase + r], s);
                atomicAdd(&red_q[obase + r], q);
            }
        }
    }
    __syncthreads();

#pragma unroll
    for (int rep = 0; rep < 4; ++rep) {
        int idx = rep * 256 + t;
        int jl = idx >> 4;
        int o8 = idx & 15;
        uint4 vv = *(const uint4*)(sY + jl * 136 + o8 * 8);
        *(uint4*)(Y + (size_t)(j0 + jl) * Mtot + o8 * 8) = vv;
    }
    if (t < 128) {
        int cp = blockIdx.x & 7;
        atomicAdd(&gs1[cp * 128 + t], red_s[t]);
        atomicAdd(&gq1[cp * 128 + t], red_q[t]);
    }
}

// ---------------------------------------------------------------------------
// Output: fused BN1 finalize (sums 8 stat copies) + BN1+ReLU + fp32 store.
__global__ __launch_bounds__(256) void k_out(const ushort_t* __restrict__ Y1,
                                             const float* __restrict__ gs1,
                                             const float* __restrict__ gq1,
                                             const float* __restrict__ gamma1,
                                             const float* __restrict__ beta1,
                                             float* __restrict__ out) {
    __shared__ float sa[128], sb[128];
    int t = threadIdx.x;
    if (t < 128) {
        float s = 0.f, q = 0.f;
#pragma unroll
        for (int k = 0; k < 8; ++k) { s += gs1[k * 128 + t]; q += gq1[k * 128 + t]; }
        float mean = s * (1.0f / 65536.0f);
        float var = q * (1.0f / 65536.0f) - mean * mean;
        float sc = gamma1[t] / sqrtf(var + 1e-5f);
        sa[t] = sc;
        sb[t] = beta1[t] - mean * sc;
    }
    __syncthreads();
    int b = blockIdx.x;
    int nl = t & 127;
    int half = t >> 7;
    int n = blockIdx.y * 128 + nl;
    const uint4* src = (const uint4*)(Y1 + (size_t)(b * 4096 + n) * 128);
    float* dst = out + (size_t)b * 128 * 4096 + n;
    uint4 raw[8];
#pragma unroll
    for (int p = 0; p < 8; ++p) raw[p] = src[half * 8 + p];
    const ushort_t* e = (const ushort_t*)raw;
#pragma unroll
    for (int c = 0; c < 64; ++c) {
        int ch = half * 64 + c;
        float v = b2f(e[c]);
        v = fmaxf(sa[ch] * v + sb[ch], 0.f);
        dst[(size_t)ch * 4096] = v;
    }
}

// ---------------------------------------------------------------------------
extern "C" void kernel_launch(void* const* d_in, const int* in_sizes, int n_in,
                              void* d_out, int out_size, void* d_ws, size_t ws_size,
                              hipStream_t stream) {
    const float* xyz1    = (const float*)d_in[0];
    const float* xyz2    = (const float*)d_in[1];
    const float* points1 = (const float*)d_in[2];
    const float* points2 = (const float*)d_in[3];
    const float* w0      = (const float*)d_in[4];
    const float* b0      = (const float*)d_in[5];
    const float* gamma0  = (const float*)d_in[6];
    const float* beta0   = (const float*)d_in[7];
    const float* w1      = (const float*)d_in[8];
    const float* b1      = (const float*)d_in[9];
    const float* gamma1  = (const float*)d_in[10];
    const float* beta1   = (const float*)d_in[11];
    float* out = (float*)d_out;

    char* ws = (char*)d_ws;
    const size_t OFF_X    = 0;                       // 67108864
    const size_t OFF_Y0   = 67108864;                // 33554432
    const size_t OFF_Y1   = 100663296;               // 16777216
    const size_t OFF_P2T  = 117440512;               // 4194304
    const size_t OFF_W0B  = 121634816;               // 262144
    const size_t OFF_W1B  = 121896960;               // 65536
    const size_t OFF_SDAT = 121965568;               // 262144
    const size_t OFF_AB   = 122227712;               // 24576 (8-way stat copies)

    ushort_t* X    = (ushort_t*)(ws + OFF_X);
    ushort_t* Y0   = (ushort_t*)(ws + OFF_Y0);
    ushort_t* Y1   = (ushort_t*)(ws + OFF_Y1);
    ushort_t* p2t  = (ushort_t*)(ws + OFF_P2T);
    ushort_t* w0b  = (ushort_t*)(ws + OFF_W0B);
    ushort_t* w1b  = (ushort_t*)(ws + OFF_W1B);
    float4* sdat   = (float4*)(ws + OFF_SDAT);
    float* ab      = (float*)(ws + OFF_AB);
    float* gs0 = ab;               float* gq0 = ab + 2048;   // 8x256 each
    float* gs1 = ab + 4096;        float* gq1 = ab + 5120;   // 8x128 each

    k_pre<<<961, 256, 0, stream>>>(w0, w0b, w1, w1b, xyz2, sdat, points2, p2t, ab);
    k_interp<<<dim3(16, 128), 256, 0, stream>>>(xyz1, sdat, points1, p2t, X);
    k_gemm<<<1024, 512, 0, stream>>>(w0b, X, b0, Y0, gs0, gq0, 256, 512);
    k_gemmf<<<1024, 256, 0, stream>>>(w1b, Y0, b1, gamma0, beta0, gs0, gq0, Y1, gs1, gq1, 128, 256);
    k_out<<<dim3(16, 32), 256, 0, stream>>>(Y1, gs1, gq1, gamma1, beta1, out);
}

// Round 12
// 204.196 us; speedup vs baseline: 1.1560x; 1.0637x over previous
//
#include <hip/hip_runtime.h>
#include <stdint.h>

typedef unsigned short ushort_t;
typedef __attribute__((ext_vector_type(8))) __bf16 bf16x8;
typedef __attribute__((ext_vector_type(4))) float f32x4;

__device__ __forceinline__ float b2f(ushort_t u) {
    unsigned v = ((unsigned)u) << 16;
    float f;
    __builtin_memcpy(&f, &v, 4);
    return f;
}

// RNE f32->bf16 via compiler cast (v_cvt path on gfx950).
__device__ __forceinline__ ushort_t f2b(float f) {
    __bf16 h = (__bf16)f;
    return __builtin_bit_cast(ushort_t, h);
}

__device__ __forceinline__ void gl_lds16(const void* g, void* l) {
    __builtin_amdgcn_global_load_lds((const __attribute__((address_space(1))) void*)g,
                                     (__attribute__((address_space(3))) void*)l, 16, 0, 0);
}

// ---------------------------------------------------------------------------
// Fused preprocessing: w0/w1 bf16-cvt, sdat build, points2 transpose, and
// zeroing of the 8-way-spread global BN-stat accumulators.
__global__ __launch_bounds__(256) void k_pre(const float* __restrict__ w0, ushort_t* __restrict__ w0b,
                                             const float* __restrict__ w1, ushort_t* __restrict__ w1b,
                                             const float* __restrict__ xyz2, float4* __restrict__ sdat,
                                             const float* __restrict__ points2, ushort_t* __restrict__ p2t,
                                             float* __restrict__ zb) {
    int bid = blockIdx.x;
    int t = threadIdx.x;
    if (bid < 512) {
        int i = bid * 256 + t;
        w0b[i] = f2b(w0[i]);
    } else if (bid < 640) {
        int i = (bid - 512) * 256 + t;
        w1b[i] = f2b(w1[i]);
    } else if (bid < 704) {
        int bb = bid - 640;
        int b = bb & 15, by = bb >> 4;
        int s = by * 256 + t;
        const float* x2 = xyz2 + (size_t)b * 3 * 1024;
        float x = x2[s], y = x2[1024 + s], z = x2[2048 + s];
        float4 v;
        v.x = x; v.y = y; v.z = z;
        v.w = __fadd_rn(__fadd_rn(__fmul_rn(x, x), __fmul_rn(y, y)), __fmul_rn(z, z));
        sdat[(size_t)b * 1024 + s] = v;
    } else if (bid < 960) {
        int bb = bid - 704;
        int b = bb & 15, sy = bb >> 4;
        int s = sy * 64 + (t & 63);
        int g = t >> 6;
        const float* src = points2 + (size_t)b * 128 * 1024 + s;
        ushort_t* dst = p2t + ((size_t)b * 1024 + s) * 128;
#pragma unroll
        for (int i = 0; i < 4; ++i) {
            int cp = i * 4 + g;
            ushort_t tmp[8];
#pragma unroll
            for (int k = 0; k < 8; ++k) tmp[k] = f2b(src[(size_t)(cp * 8 + k) * 1024]);
            *(uint4*)(dst + cp * 8) = *(const uint4*)tmp;
        }
    } else {
        // zero 8-way stat copies: gs0[8][256] gq0[8][256] gs1[8][128] gq1[8][128]
        for (int i = t; i < 6144; i += 256) zb[i] = 0.f;
    }
}

// ---------------------------------------------------------------------------
// 3-NN + build X [65536][512] bf16 (proven 46-48us version: 32 q/block,
// LDS-staged sdat, p1-hoist, sidx/sw aliased into dead sP region).
// Scan/merge math bit-identical to the verified version.
__global__ __launch_bounds__(256) void k_interp(const float* __restrict__ xyz1,
                                                const float4* __restrict__ sdat,
                                                const float* __restrict__ points1,
                                                const ushort_t* __restrict__ p2t,
                                                ushort_t* __restrict__ X) {
    int b = blockIdx.x;
    int n0 = blockIdx.y * 32;
    int t = threadIdx.x;
    int tq = t & 31;        // query within block
    int slice = t >> 5;     // 0..7
    int wave = t >> 6, lane = t & 63;

    __shared__ __align__(16) char sbuf[16384];  // sP during scan; sidx/sw after
    float4* sP = (float4*)sbuf;                 // 1024 float4 staged sdat[b]
    int*   sidx = (int*)sbuf;                   // 32*3 ints   (after scan)
    float* sw   = (float*)(sbuf + 384);         // 32*3 floats (after scan)
    __shared__ float sD[768];
    __shared__ int   sI[768];

    // stage sdat[b] -> LDS (wave w loads points [w*256, w*256+256))
    {
        const float4* src = sdat + (size_t)b * 1024;
#pragma unroll
        for (int c = 0; c < 4; ++c) {
            int p = wave * 256 + c * 64 + lane;
            gl_lds16(src + p, sbuf + p * 16);
        }
    }

    int n = n0 + tq;
    float x = xyz1[((size_t)b * 3 + 0) * 4096 + n];
    float y = xyz1[((size_t)b * 3 + 1) * 4096 + n];
    float z = xyz1[((size_t)b * 3 + 2) * 4096 + n];
    float s1 = __fadd_rn(__fadd_rn(__fmul_rn(x, x), __fmul_rn(y, y)), __fmul_rn(z, z));

    __syncthreads();   // staging complete (drains all vmcnt incl. gl_lds)

    // Issue points1 loads now: they ride out the scan in the vmem queue.
    const float* p1base = points1 + (size_t)b * 128 * 4096 + n0 + tq;
    float p1v[16];
#pragma unroll
    for (int i = 0; i < 2; ++i)
#pragma unroll
        for (int k = 0; k < 8; ++k)
            p1v[i * 8 + k] = p1base[(size_t)(((i * 8 + slice) * 8) + k) * 4096];

    float d0 = 1e30f, d1 = 1e30f, d2 = 1e30f;
    int i0 = 0, i1 = 0, i2 = 0;
    int sbeg = slice * 128;
    const float4* sdL = sP + sbeg;
#pragma unroll 8
    for (int s = 0; s < 128; ++s) {
        float4 v = sdL[s];
        float dot = fmaf(z, v.z, fmaf(y, v.y, __fmul_rn(x, v.x)));
        // fmaf(-2,dot,s1) == add(mul(-2,dot),s1) bit-exactly: *2 is exact.
        float d = __fadd_rn(fmaf(-2.0f, dot, s1), v.w);
        int si = sbeg + s;
        bool c0 = d < d0, c1 = d < d1, c2 = d < d2;
        // indices: identical logic to the verified version
        i2 = c1 ? i1 : (c2 ? si : i2);
        i1 = c0 ? i0 : (c1 ? si : i1);
        i0 = c0 ? si : i0;
        // distances: min/max forms select bit-identical values
        d2 = fminf(fmaxf(d, d1), d2);
        d1 = fminf(fmaxf(d, d0), d1);
        d0 = fminf(d, d0);
    }
    sD[t * 3 + 0] = d0; sD[t * 3 + 1] = d1; sD[t * 3 + 2] = d2;
    sI[t * 3 + 0] = i0; sI[t * 3 + 1] = i1; sI[t * 3 + 2] = i2;

    // points1 part: X[j][0:128] = bf16(points1[b][:, n]) (loads done above)
    {
        ushort_t* dstbase = X + (size_t)(b * 4096 + n0 + tq) * 512;
#pragma unroll
        for (int i = 0; i < 2; ++i) {
            int piece = i * 8 + slice;
            ushort_t tmp[8];
#pragma unroll
            for (int k = 0; k < 8; ++k) tmp[k] = f2b(p1v[i * 8 + k]);
            *(uint4*)(dstbase + piece * 8) = *(const uint4*)tmp;
        }
    }
    __syncthreads();   // scan + sD/sI complete; sP now dead

    // merge: threads t<32 pick global top-3 of 24 candidates by lex (d, idx).
    if (t < 32) {
        int sel0 = -1, sel1 = -1;
        float seld[3]; int seli[3];
#pragma unroll
        for (int r = 0; r < 3; ++r) {
            float bd = 1e38f; int bi = 1 << 30;
            for (int k = 0; k < 24; ++k) {
                int s3 = (k * 0xAAAB) >> 17;    // k/3 for k<=23
                int rank = k - s3 * 3;
                int base = (s3 * 32 + t) * 3 + rank;
                float cd = sD[base];
                int ci = sI[base];
                bool excl = (ci == sel0) | (ci == sel1);
                bool better = (!excl) & ((cd < bd) | ((cd == bd) & (ci < bi)));
                if (better) { bd = cd; bi = ci; }
            }
            seld[r] = bd; seli[r] = bi;
            if (r == 0) sel0 = bi; else if (r == 1) sel1 = bi;
        }
        float r0 = 1.0f / (seld[0] + 1e-8f);
        float r1 = 1.0f / (seld[1] + 1e-8f);
        float r2 = 1.0f / (seld[2] + 1e-8f);
        float rs = r0 + r1 + r2;
        sw[t * 3 + 0] = r0 / rs; sw[t * 3 + 1] = r1 / rs; sw[t * 3 + 2] = r2 / rs;
        sidx[t * 3 + 0] = seli[0]; sidx[t * 3 + 1] = seli[1]; sidx[t * 3 + 2] = seli[2];
    }
    __syncthreads();

    // gather: 32 queries x 48 pieces = 1536 items
#pragma unroll
    for (int i = 0; i < 6; ++i) {
        int idx = i * 256 + t;
        int q = idx / 48;
        int rem = idx - q * 48;
        int r = rem >> 4;
        int piece = rem & 15;
        int si = sidx[q * 3 + r] & 1023;   // clamp: defensive, free
        float wt = sw[q * 3 + r];
        const ushort_t* src = p2t + ((size_t)b * 1024 + si) * 128 + piece * 8;
        uint4 raw = *(const uint4*)src;
        ushort_t* e = (ushort_t*)&raw;
        ushort_t outv[8];
#pragma unroll
        for (int k = 0; k < 8; ++k) outv[k] = f2b(wt * b2f(e[k]));
        ushort_t* dst = X + (size_t)(b * 4096 + n0 + q) * 512 + 128 + r * 128 + piece * 8;
        *(uint4*)dst = *(const uint4*)outv;
    }
}

// ---------------------------------------------------------------------------
// GEMM0: EXACT round-5 structure (best measured total: 212.7us) — BM=256,
// one block per j-tile, 512 thr (8 waves = 4m x 2n), LINEAR gl_lds16 staging
// (NO swizzle: rounds 9-11 showed pre-swizzled gl_lds16 SOURCE addresses
// cost more in staging coalescing than the bank-conflict fix recovers).
// Only delta vs round 5: stats go to 8-way-spread global accumulators.
__global__ __launch_bounds__(512, 4) void k_gemm(const ushort_t* __restrict__ A,
                                                 const ushort_t* __restrict__ Bt,
                                                 const float* __restrict__ bias,
                                                 ushort_t* __restrict__ Y,
                                                 float* __restrict__ gs,
                                                 float* __restrict__ gq,
                                                 int Mtot, int K) {
    __shared__ __align__(16) char smem[51200];
    ushort_t* As = (ushort_t*)smem;               // 256 x 64 bf16 = 32 KB
    ushort_t* Bs = (ushort_t*)(smem + 32768);     // 128 x 64 bf16 = 16 KB
    ushort_t* sY = (ushort_t*)smem;               // 128 x 136 epilogue (34816 B)
    float* red_s = (float*)(smem + 49152);        // 256 floats
    float* red_q = red_s + 256;                   // 256 floats

    int t = threadIdx.x;
    int j0 = blockIdx.x * 128;
    int wave = t >> 6, lane = t & 63;
    int wm = wave >> 1, wn = wave & 1;            // wm 0..3 (m), wn 0..1 (j)
    int l16 = lane & 15, quad = lane >> 4;

    if (t < 256) { red_s[t] = 0.f; red_q[t] = 0.f; }

    f32x4 acc[4][4] = {};

    int nk = K >> 6;
    for (int kt = 0; kt < nk; ++kt) {
#pragma unroll
        for (int c = 0; c < 4; ++c) {
            int idx = c * 512 + t;
            int row = idx >> 3, kc = idx & 7;
            gl_lds16(A + (size_t)row * K + kt * 64 + kc * 8, As + idx * 8);
        }
#pragma unroll
        for (int c = 0; c < 2; ++c) {
            int idx = c * 512 + t;
            int row = idx >> 3, kc = idx & 7;
            gl_lds16(Bt + (size_t)(j0 + row) * K + kt * 64 + kc * 8, Bs + idx * 8);
        }
        __syncthreads();

#pragma unroll
        for (int kk = 0; kk < 2; ++kk) {
            bf16x8 af[4], bfr[4];
#pragma unroll
            for (int mi = 0; mi < 4; ++mi)
                af[mi] = *(const bf16x8*)(As + (wm * 64 + mi * 16 + l16) * 64 + kk * 32 + quad * 8);
#pragma unroll
            for (int ni = 0; ni < 4; ++ni)
                bfr[ni] = *(const bf16x8*)(Bs + (wn * 64 + ni * 16 + l16) * 64 + kk * 32 + quad * 8);
#pragma unroll
            for (int mi = 0; mi < 4; ++mi)
#pragma unroll
                for (int ni = 0; ni < 4; ++ni)
                    acc[mi][ni] = __builtin_amdgcn_mfma_f32_16x16x32_bf16(af[mi], bfr[ni], acc[mi][ni], 0, 0, 0);
        }
        __syncthreads();
    }

    // epilogue: two m-halves through the 128x136 sY staging region
#pragma unroll
    for (int h = 0; h < 2; ++h) {
        if ((wm >> 1) == h) {
#pragma unroll
            for (int mi = 0; mi < 4; ++mi) {
                int obase = wm * 64 + mi * 16 + quad * 4;    // absolute channel
                int ocol = obase - h * 128;                  // 0..124 in half
                float bv[4];
#pragma unroll
                for (int r = 0; r < 4; ++r) bv[r] = bias[obase + r];
                float sr[4] = {0.f, 0.f, 0.f, 0.f}, qr[4] = {0.f, 0.f, 0.f, 0.f};
#pragma unroll
                for (int ni = 0; ni < 4; ++ni) {
                    int j_local = wn * 64 + ni * 16 + l16;
                    ushort4 pk;
                    float v0 = acc[mi][ni][0] + bv[0];
                    float v1 = acc[mi][ni][1] + bv[1];
                    float v2 = acc[mi][ni][2] + bv[2];
                    float v3 = acc[mi][ni][3] + bv[3];
                    pk.x = f2b(v0); pk.y = f2b(v1); pk.z = f2b(v2); pk.w = f2b(v3);
                    sr[0] += v0; qr[0] += v0 * v0;
                    sr[1] += v1; qr[1] += v1 * v1;
                    sr[2] += v2; qr[2] += v2 * v2;
                    sr[3] += v3; qr[3] += v3 * v3;
                    *(ushort4*)(sY + j_local * 136 + ocol) = pk;
                }
#pragma unroll
                for (int r = 0; r < 4; ++r) {
                    float s = sr[r], q = qr[r];
                    s += __shfl_xor(s, 1); s += __shfl_xor(s, 2);
                    s += __shfl_xor(s, 4); s += __shfl_xor(s, 8);
                    q += __shfl_xor(q, 1); q += __shfl_xor(q, 2);
                    q += __shfl_xor(q, 4); q += __shfl_xor(q, 8);
                    if (l16 == 0) {
                        atomicAdd(&red_s[obase + r], s);
                        atomicAdd(&red_q[obase + r], q);
                    }
                }
            }
        }
        __syncthreads();
#pragma unroll
        for (int rep = 0; rep < 4; ++rep) {
            int idx = rep * 512 + t;
            int jl = idx >> 4;
            int o8 = idx & 15;
            uint4 vv = *(const uint4*)(sY + jl * 136 + o8 * 8);
            *(uint4*)(Y + (size_t)(j0 + jl) * Mtot + h * 128 + o8 * 8) = vv;
        }
        __syncthreads();
    }
    if (t < 256) {
        int cp = blockIdx.x & 7;
        atomicAdd(&gs[cp * 256 + t], red_s[t]);
        atomicAdd(&gq[cp * 256 + t], red_q[t]);
    }
}

// ---------------------------------------------------------------------------
// GEMM1: EXACT round-5 structure (BM=128 x BN=128, 256thr, grid (1,512),
// LINEAR staging) + fused BN0 finalize in prologue (sums 8 stat copies)
// + BN0+ReLU at B staging + atomic stats out.
__global__ __launch_bounds__(256) void k_gemmf(const ushort_t* __restrict__ A,
                                               const ushort_t* __restrict__ Y0,
                                               const float* __restrict__ bias,
                                               const float* __restrict__ gamma0,
                                               const float* __restrict__ beta0,
                                               const float* __restrict__ gs0,
                                               const float* __restrict__ gq0,
                                               ushort_t* __restrict__ Y,
                                               float* __restrict__ gs1,
                                               float* __restrict__ gq1,
                                               int Mtot, int K) {
    __shared__ __align__(16) char smem[35840];
    ushort_t* As = (ushort_t*)smem;               // 128 x 64 = 16 KB
    ushort_t* Bs = (ushort_t*)(smem + 16384);     // 128 x 64 = 16 KB
    float* sa = (float*)(smem + 32768);           // 256 floats
    float* sb = (float*)(smem + 33792);           // 256 floats
    ushort_t* sY = (ushort_t*)smem;               // epilogue reuse
    float* red_s = (float*)(smem + 34816);
    float* red_q = red_s + 128;

    int t = threadIdx.x;
    int m0 = blockIdx.x * 128;
    int j0 = blockIdx.y * 128;
    int wave = t >> 6, lane = t & 63;
    int wm = wave >> 1, wn = wave & 1;
    int l16 = lane & 15, quad = lane >> 4;

    // BN0 finalize (sum 8 spread copies; identical math to former k_bnfin)
    {
        float s = 0.f, q = 0.f;
#pragma unroll
        for (int k = 0; k < 8; ++k) { s += gs0[k * 256 + t]; q += gq0[k * 256 + t]; }
        float mean = s * (1.0f / 65536.0f);
        float var = q * (1.0f / 65536.0f) - mean * mean;
        float sc = gamma0[t] / sqrtf(var + 1e-5f);
        sa[t] = sc;
        sb[t] = beta0[t] - mean * sc;
    }
    if (t < 128) { red_s[t] = 0.f; red_q[t] = 0.f; }
    __syncthreads();

    f32x4 acc[4][4] = {};

    int nk = K >> 6;
    for (int kt = 0; kt < nk; ++kt) {
#pragma unroll
        for (int c = 0; c < 4; ++c) {
            int idx = c * 256 + t;
            int row = idx >> 3, kc = idx & 7;
            gl_lds16(A + (size_t)(m0 + row) * K + kt * 64 + kc * 8, As + idx * 8);
        }
#pragma unroll
        for (int c = 0; c < 4; ++c) {
            int idx = c * 256 + t;
            int row = idx >> 3, kc = idx & 7;
            int cbase = kt * 64 + kc * 8;
            uint4 raw = *(const uint4*)(Y0 + (size_t)(j0 + row) * K + cbase);
            ushort_t* e = (ushort_t*)&raw;
            ushort_t outv[8];
#pragma unroll
            for (int k = 0; k < 8; ++k) {
                float v = fmaxf(sa[cbase + k] * b2f(e[k]) + sb[cbase + k], 0.f);
                outv[k] = f2b(v);
            }
            *(uint4*)(Bs + idx * 8) = *(const uint4*)outv;
        }
        __syncthreads();

#pragma unroll
        for (int kk = 0; kk < 2; ++kk) {
            bf16x8 af[4], bfr[4];
#pragma unroll
            for (int mi = 0; mi < 4; ++mi)
                af[mi] = *(const bf16x8*)(As + (wm * 64 + mi * 16 + l16) * 64 + kk * 32 + quad * 8);
#pragma unroll
            for (int ni = 0; ni < 4; ++ni)
                bfr[ni] = *(const bf16x8*)(Bs + (wn * 64 + ni * 16 + l16) * 64 + kk * 32 + quad * 8);
#pragma unroll
            for (int mi = 0; mi < 4; ++mi)
#pragma unroll
                for (int ni = 0; ni < 4; ++ni)
                    acc[mi][ni] = __builtin_amdgcn_mfma_f32_16x16x32_bf16(af[mi], bfr[ni], acc[mi][ni], 0, 0, 0);
        }
        __syncthreads();
    }

#pragma unroll
    for (int mi = 0; mi < 4; ++mi) {
        int obase = wm * 64 + mi * 16 + quad * 4;
        float bv[4];
#pragma unroll
        for (int r = 0; r < 4; ++r) bv[r] = bias[m0 + obase + r];
        float sr[4] = {0.f, 0.f, 0.f, 0.f}, qr[4] = {0.f, 0.f, 0.f, 0.f};
#pragma unroll
        for (int ni = 0; ni < 4; ++ni) {
            int j_local = wn * 64 + ni * 16 + l16;
            ushort4 pk;
            float v0 = acc[mi][ni][0] + bv[0];
            float v1 = acc[mi][ni][1] + bv[1];
            float v2 = acc[mi][ni][2] + bv[2];
            float v3 = acc[mi][ni][3] + bv[3];
            pk.x = f2b(v0); pk.y = f2b(v1); pk.z = f2b(v2); pk.w = f2b(v3);
            sr[0] += v0; qr[0] += v0 * v0;
            sr[1] += v1; qr[1] += v1 * v1;
            sr[2] += v2; qr[2] += v2 * v2;
            sr[3] += v3; qr[3] += v3 * v3;
            *(ushort4*)(sY + j_local * 136 + obase) = pk;
        }
#pragma unroll
        for (int r = 0; r < 4; ++r) {
            float s = sr[r], q = qr[r];
            s += __shfl_xor(s, 1); s += __shfl_xor(s, 2);
            s += __shfl_xor(s, 4); s += __shfl_xor(s, 8);
            q += __shfl_xor(q, 1); q += __shfl_xor(q, 2);
            q += __shfl_xor(q, 4); q += __shfl_xor(q, 8);
            if (l16 == 0) {
                atomicAdd(&red_s[obase + r], s);
                atomicAdd(&red_q[obase + r], q);
            }
        }
    }
    __syncthreads();

#pragma unroll
    for (int rep = 0; rep < 8; ++rep) {
        int idx = rep * 256 + t;
        int jl = idx >> 4;
        int o8 = idx & 15;
        uint4 vv = *(const uint4*)(sY + jl * 136 + o8 * 8);
        *(uint4*)(Y + (size_t)(j0 + jl) * Mtot + m0 + o8 * 8) = vv;
    }
    if (t < 128) {
        int cp = blockIdx.y & 7;
        atomicAdd(&gs1[cp * 128 + m0 + t], red_s[t]);
        atomicAdd(&gq1[cp * 128 + m0 + t], red_q[t]);
    }
}

// ---------------------------------------------------------------------------
// Output: fused BN1 finalize (sums 8 stat copies) + BN1+ReLU + fp32 store.
__global__ __launch_bounds__(256) void k_out(const ushort_t* __restrict__ Y1,
                                             const float* __restrict__ gs1,
                                             const float* __restrict__ gq1,
                                             const float* __restrict__ gamma1,
                                             const float* __restrict__ beta1,
                                             float* __restrict__ out) {
    __shared__ float sa[128], sb[128];
    int t = threadIdx.x;
    if (t < 128) {
        float s = 0.f, q = 0.f;
#pragma unroll
        for (int k = 0; k < 8; ++k) { s += gs1[k * 128 + t]; q += gq1[k * 128 + t]; }
        float mean = s * (1.0f / 65536.0f);
        float var = q * (1.0f / 65536.0f) - mean * mean;
        float sc = gamma1[t] / sqrtf(var + 1e-5f);
        sa[t] = sc;
        sb[t] = beta1[t] - mean * sc;
    }
    __syncthreads();
    int b = blockIdx.x;
    int nl = t & 127;
    int half = t >> 7;
    int n = blockIdx.y * 128 + nl;
    const uint4* src = (const uint4*)(Y1 + (size_t)(b * 4096 + n) * 128);
    float* dst = out + (size_t)b * 128 * 4096 + n;
    uint4 raw[8];
#pragma unroll
    for (int p = 0; p < 8; ++p) raw[p] = src[half * 8 + p];
    const ushort_t* e = (const ushort_t*)raw;
#pragma unroll
    for (int c = 0; c < 64; ++c) {
        int ch = half * 64 + c;
        float v = b2f(e[c]);
        v = fmaxf(sa[ch] * v + sb[ch], 0.f);
        dst[(size_t)ch * 4096] = v;
    }
}

// ---------------------------------------------------------------------------
extern "C" void kernel_launch(void* const* d_in, const int* in_sizes, int n_in,
                              void* d_out, int out_size, void* d_ws, size_t ws_size,
                              hipStream_t stream) {
    const float* xyz1    = (const float*)d_in[0];
    const float* xyz2    = (const float*)d_in[1];
    const float* points1 = (const float*)d_in[2];
    const float* points2 = (const float*)d_in[3];
    const float* w0      = (const float*)d_in[4];
    const float* b0      = (const float*)d_in[5];
    const float* gamma0  = (const float*)d_in[6];
    const float* beta0   = (const float*)d_in[7];
    const float* w1      = (const float*)d_in[8];
    const float* b1      = (const float*)d_in[9];
    const float* gamma1  = (const float*)d_in[10];
    const float* beta1   = (const float*)d_in[11];
    float* out = (float*)d_out;

    char* ws = (char*)d_ws;
    const size_t OFF_X    = 0;                       // 67108864
    const size_t OFF_Y0   = 67108864;                // 33554432
    const size_t OFF_Y1   = 100663296;               // 16777216
    const size_t OFF_P2T  = 117440512;               // 4194304
    const size_t OFF_W0B  = 121634816;               // 262144
    const size_t OFF_W1B  = 121896960;               // 65536
    const size_t OFF_SDAT = 121965568;               // 262144
    const size_t OFF_AB   = 122227712;               // 24576 (8-way stat copies)

    ushort_t* X    = (ushort_t*)(ws + OFF_X);
    ushort_t* Y0   = (ushort_t*)(ws + OFF_Y0);
    ushort_t* Y1   = (ushort_t*)(ws + OFF_Y1);
    ushort_t* p2t  = (ushort_t*)(ws + OFF_P2T);
    ushort_t* w0b  = (ushort_t*)(ws + OFF_W0B);
    ushort_t* w1b  = (ushort_t*)(ws + OFF_W1B);
    float4* sdat   = (float4*)(ws + OFF_SDAT);
    float* ab      = (float*)(ws + OFF_AB);
    float* gs0 = ab;               float* gq0 = ab + 2048;   // 8x256 each
    float* gs1 = ab + 4096;        float* gq1 = ab + 5120;   // 8x128 each

    k_pre<<<961, 256, 0, stream>>>(w0, w0b, w1, w1b, xyz2, sdat, points2, p2t, ab);
    k_interp<<<dim3(16, 128), 256, 0, stream>>>(xyz1, sdat, points1, p2t, X);
    k_gemm<<<512, 512, 0, stream>>>(w0b, X, b0, Y0, gs0, gq0, 256, 512);
    k_gemmf<<<dim3(1, 512), 256, 0, stream>>>(w1b, Y0, b1, gamma0, beta0, gs0, gq0, Y1, gs1, gq1, 128, 256);
    k_out<<<dim3(16, 32), 256, 0, stream>>>(Y1, gs1, gq1, gamma1, beta1, out);
}